// Round 1
// 733.034 us; speedup vs baseline: 1.1091x; 1.1091x over previous
//
#include <hip/hip_runtime.h>

typedef __bf16 bf16;
typedef __bf16 bf16x4 __attribute__((ext_vector_type(4)));
typedef __bf16 bf16x8 __attribute__((ext_vector_type(8)));
typedef float f32x4 __attribute__((ext_vector_type(4)));

#define LOG2E 1.44269504088896340736f
// 1/sqrt(128) * log2(e), folded into Q at projection time -> softmax runs in log2 domain
#define QSCALE 0.12751884935f
// defer-max threshold (log2 domain): skip O-rescale while max grows <= 8 -> P <= 256
#define RESCALE_THR 8.0f

// ---------------- async global->LDS (width 16) ----------------
__device__ __forceinline__ void gload_lds16(const void* gp, void* lp) {
    __builtin_amdgcn_global_load_lds(
        (__attribute__((address_space(1))) void*)gp,
        (__attribute__((address_space(3))) void*)lp,
        16, 0, 0);
}

// XOR swizzle of 16B-chunk index within a row (low 3 bits), self-inverse.
__device__ __forceinline__ int swz(int j, int row) {
    return (j & 8) | ((j ^ row) & 7);
}

// ---------------- DPP 16-lane row reductions (VALU pipe, no LDS) ----------------
template <int CTRL>
__device__ __forceinline__ float dpp_mov(float x) {
    return __int_as_float(__builtin_amdgcn_update_dpp(
        0, __float_as_int(x), CTRL, 0xF, 0xF, true));
}
// ROW_ROR:n = 0x120|n ; rotation-based allreduce over the 16-lane DPP row
__device__ __forceinline__ float rowmax16(float v) {
    v = fmaxf(v, dpp_mov<0x121>(v));
    v = fmaxf(v, dpp_mov<0x122>(v));
    v = fmaxf(v, dpp_mov<0x124>(v));
    v = fmaxf(v, dpp_mov<0x128>(v));
    return v;
}
__device__ __forceinline__ float rowsum16(float v) {
    v += dpp_mov<0x121>(v);
    v += dpp_mov<0x122>(v);
    v += dpp_mov<0x124>(v);
    v += dpp_mov<0x128>(v);
    return v;
}

// ---------------- fp32 -> bf16 convert ----------------
__global__ void conv_bf16(const float* __restrict__ in, bf16* __restrict__ out, int n4) {
    int i = blockIdx.x * 256 + threadIdx.x;
    if (i < n4) {
        float4 f = ((const float4*)in)[i];
        bf16x4 v;
        v[0] = (bf16)f.x; v[1] = (bf16)f.y; v[2] = (bf16)f.z; v[3] = (bf16)f.w;
        *(bf16x4*)(out + (size_t)i * 4) = v;
    }
}

// ---------------- cached_k -> d_out(k, t<2048) fp32 + kb bf16 ----------------
__global__ void copy_cache_k(const float* __restrict__ ck, float* __restrict__ kout,
                             bf16* __restrict__ kb) {
    size_t i = ((size_t)blockIdx.x * 256 + threadIdx.x) * 4;
    size_t bh  = i >> 18;
    size_t rem = i & 262143;
    size_t o   = (bh << 19) + rem;
    float4 f = *(const float4*)(ck + i);
    *(float4*)(kout + o) = f;
    bf16x4 v;
    v[0] = (bf16)f.x; v[1] = (bf16)f.y; v[2] = (bf16)f.z; v[3] = (bf16)f.w;
    *(bf16x4*)(kb + o) = v;
}

// ---------------- cached_v -> d_out(v, t<2048) fp32 + vtb bf16 transposed ----------------
__global__ void copy_cache_v(const float* __restrict__ cv, float* __restrict__ vout,
                             bf16* __restrict__ vtb) {
    __shared__ float tile[32][33];
    int bh = blockIdx.z;
    int t0 = blockIdx.x * 32;
    int dh0 = blockIdx.y * 32;
    int tx = threadIdx.x, ty = threadIdx.y;
    const float* src = cv + (size_t)bh * 2048 * 128;
    float* dstf = vout + (size_t)bh * 4096 * 128;
    #pragma unroll
    for (int i = 0; i < 4; ++i) {
        int t = t0 + ty * 4 + i;
        float val = src[(size_t)t * 128 + dh0 + tx];
        dstf[(size_t)t * 128 + dh0 + tx] = val;
        tile[ty * 4 + i][tx] = val;
    }
    __syncthreads();
    bf16* dstb = vtb + (size_t)bh * 128 * 4096;
    #pragma unroll
    for (int i = 0; i < 4; ++i) {
        int dh = dh0 + ty * 4 + i;
        dstb[(size_t)dh * 4096 + t0 + tx] = (bf16)tile[tx][ty * 4 + i];
    }
}

// ---------------- NT GEMM: C[M,N] = A[M,K] * B[N,K]^T, bf16 in, fp32 acc ----------------
// 2-phase double-buffered: STAGE(next) -> compute(cur) -> __syncthreads (implicit vmcnt(0))
template <int MODE>
__global__ __launch_bounds__(256)
void gemm_nt(const bf16* __restrict__ A, const bf16* __restrict__ Bm,
             float* __restrict__ out_f32, bf16* __restrict__ out_bf16) {
    const int K = 2048, N = 2048;
    __shared__ __align__(16) char smem[32768];  // 2 x (A 8K + B 8K)
    const int tid = threadIdx.x;
    const int wid = tid >> 6;
    const int lane = tid & 63;
    const int quad = lane >> 4;
    const int l16 = lane & 15;
    const int m0 = blockIdx.y * 128;
    const int n0 = blockIdx.x * 128;
    const int wm = (wid & 1) * 64;
    const int wn = (wid >> 1) * 64;

    f32x4 zero = {0.f, 0.f, 0.f, 0.f};
    f32x4 acc[4][4];
    #pragma unroll
    for (int i = 0; i < 4; ++i)
        #pragma unroll
        for (int j = 0; j < 4; ++j) acc[i][j] = zero;

    auto stage = [&](int k0, int buf) {
        char* base = smem + buf * 16384;
        #pragma unroll
        for (int t = 0; t < 2; ++t) {
            int c = t * 256 + tid;
            int row = c >> 2, kc = c & 3;
            const char* gA = (const char*)(A + (size_t)(m0 + row) * K + k0 + kc * 8);
            const char* gB = (const char*)(Bm + (size_t)(n0 + row) * K + k0 + kc * 8);
            char* lA = base + (size_t)(t * 256 + (tid & ~63)) * 16;
            char* lB = base + 8192 + (size_t)(t * 256 + (tid & ~63)) * 16;
            gload_lds16(gA, lA);
            gload_lds16(gB, lB);
        }
    };

    stage(0, 0);
    __syncthreads();

    for (int k0 = 0; k0 < K; k0 += 32) {
        const int cur = (k0 >> 5) & 1;
        if (k0 + 32 < K) stage(k0 + 32, cur ^ 1);
        const char* base = smem + cur * 16384;
        bf16x8 af[4], bfv[4];
        #pragma unroll
        for (int i = 0; i < 4; ++i) {
            af[i]  = *(const bf16x8*)(base + ((wm + i * 16 + l16) * 32 + quad * 8) * 2);
            bfv[i] = *(const bf16x8*)(base + 8192 + ((wn + i * 16 + l16) * 32 + quad * 8) * 2);
        }
        __builtin_amdgcn_s_setprio(1);
        #pragma unroll
        for (int i = 0; i < 4; ++i)
            #pragma unroll
            for (int j = 0; j < 4; ++j)
                acc[i][j] = __builtin_amdgcn_mfma_f32_16x16x32_bf16(af[i], bfv[j], acc[i][j], 0, 0, 0);
        __builtin_amdgcn_s_setprio(0);
        __syncthreads();  // drains vmcnt(0): next buffer ready; all waves done with cur
    }

    #pragma unroll
    for (int i = 0; i < 4; ++i)
        #pragma unroll
        for (int j = 0; j < 4; ++j)
            #pragma unroll
            for (int r = 0; r < 4; ++r) {
                int grow = m0 + wm + i * 16 + quad * 4 + r;
                int gcol = n0 + wn + j * 16 + l16;
                float v = acc[i][j][r];
                if (MODE == 0) {
                    out_f32[(size_t)grow * N + gcol] = v;
                } else {
                    int b = grow >> 11, s = grow & 2047;
                    int h = gcol >> 7, dh = gcol & 127;
                    if (MODE == 1) {
                        out_bf16[(((size_t)(b * 16 + h) * 2048) + s) * 128 + dh] = (bf16)(v * QSCALE);
                    } else if (MODE == 2) {
                        size_t idx = (((size_t)(b * 16 + h) * 4096) + 2048 + s) * 128 + dh;
                        out_f32[idx] = v;
                        out_bf16[idx] = (bf16)v;
                    } else {
                        size_t idx = (((size_t)(b * 16 + h) * 4096) + 2048 + s) * 128 + dh;
                        out_f32[idx] = v;
                        out_bf16[(((size_t)(b * 16 + h) * 128) + dh) * 4096 + 2048 + s] = (bf16)v;
                    }
                }
            }
}

// ---------------- flash attention v4 ----------------
// qb (B,H,2048,128) bf16 PRE-SCALED; kb (B,H,4096,128); vtb (B,H,128,4096) -> ab (B,S,2048)
// v4: double-buffered K/V with async prefetch (2-phase), defer-max rescale (THR=8, log2
// domain), setprio(1) around MFMA clusters, pbuf halved to 1 region/wave (per-qi reuse).
// LDS: 2 x (K 16K + V 16K) = 64K at [0,65536) + pbuf 4x2176 at [65536,74240) -> 2 blk/CU.
__global__ __launch_bounds__(256, 2)
void flash_attn(const bf16* __restrict__ qb, const bf16* __restrict__ kb,
                const bf16* __restrict__ vtb, bf16* __restrict__ ab) {
    __shared__ __align__(16) char smem[74240];
    const int tid = threadIdx.x;
    const int wid = tid >> 6;
    const int lane = tid & 63;
    const int quad = lane >> 4;
    const int l16 = lane & 15;

    // XCD swizzle: flat = 512 blocks; same head -> same XCD
    const int flat = blockIdx.x;
    const int xcd = flat & 7;
    const int idx = flat >> 3;
    const int bh = xcd * 4 + (idx >> 4);
    const int qblk = idx & 15;
    const int b = bh >> 4, h = bh & 15;
    const int s0 = qblk * 128 + wid * 32;

    const bf16* Q  = qb  + (size_t)bh * 2048 * 128;
    const bf16* Kp = kb  + (size_t)bh * 4096 * 128;
    const bf16* Vt = vtb + (size_t)bh * 128 * 4096;

    bf16x8 qf[2][4];
    #pragma unroll
    for (int qi = 0; qi < 2; ++qi)
        #pragma unroll
        for (int ks = 0; ks < 4; ++ks)
            qf[qi][ks] = *(const bf16x8*)(Q + (size_t)(s0 + qi * 16 + l16) * 128 + ks * 32 + quad * 8);

    f32x4 zero = {0.f, 0.f, 0.f, 0.f};
    f32x4 oacc[2][8];
    float mrun[2][4], lrun[2][4];
    #pragma unroll
    for (int qi = 0; qi < 2; ++qi) {
        #pragma unroll
        for (int i = 0; i < 8; ++i) oacc[qi][i] = zero;
        #pragma unroll
        for (int r = 0; r < 4; ++r) { mrun[qi][r] = -1e30f; lrun[qi][r] = 0.f; }
    }

    auto stage = [&](int t0, int buf) {
        char* Kb = smem + buf * 32768;
        char* Vb = Kb + 16384;
        #pragma unroll
        for (int r = 0; r < 4; ++r) {
            int kc = r * 256 + tid;
            int row = kc >> 4, p = kc & 15;
            int j = swz(p, row);
            gload_lds16(Kp + (size_t)(t0 + row) * 128 + j * 8, Kb + kc * 16);
        }
        #pragma unroll
        for (int r = 0; r < 4; ++r) {
            int vc = r * 256 + tid;
            int row = vc >> 3, p = vc & 7;
            int j = (p ^ row) & 7;
            gload_lds16(Vt + (size_t)row * 4096 + t0 + j * 8, Vb + vc * 16);
        }
    };

    stage(0, 0);
    __syncthreads();  // implicit vmcnt(0): buf0 resident

    for (int t0 = 0; t0 < 4096; t0 += 64) {
        const int cur = (t0 >> 6) & 1;
        // prefetch next tile into the other buffer; lands under this tile's compute
        if (t0 + 64 < 4096) stage(t0 + 64, cur ^ 1);
        const char* Ksh = smem + cur * 32768;
        const char* Vsh = Ksh + 16384;

        // ---- QK^T ----
        f32x4 sacc[2][4];
        #pragma unroll
        for (int qi = 0; qi < 2; ++qi)
            #pragma unroll
            for (int nt = 0; nt < 4; ++nt) sacc[qi][nt] = zero;
        __builtin_amdgcn_s_setprio(1);
        #pragma unroll
        for (int nt = 0; nt < 4; ++nt) {
            #pragma unroll
            for (int ks = 0; ks < 4; ++ks) {
                bf16x8 kf = *(const bf16x8*)(Ksh + (nt * 16 + l16) * 256 + swz(ks * 4 + quad, l16) * 16);
                sacc[0][nt] = __builtin_amdgcn_mfma_f32_16x16x32_bf16(qf[0][ks], kf, sacc[0][nt], 0, 0, 0);
                sacc[1][nt] = __builtin_amdgcn_mfma_f32_16x16x32_bf16(qf[1][ks], kf, sacc[1][nt], 0, 0, 0);
            }
        }
        __builtin_amdgcn_s_setprio(0);

        // ---- online softmax (log2 domain), DPP row reductions, defer-max ----
        bf16x8 pf[2][2];
        char* pb = smem + 65536 + wid * 2176;  // one region/wave, reused across qi
        #pragma unroll
        for (int qi = 0; qi < 2; ++qi) {
            float mx[4];
            #pragma unroll
            for (int r = 0; r < 4; ++r) {
                float v0 = fmaxf(fmaxf(sacc[qi][0][r], sacc[qi][1][r]),
                                 fmaxf(sacc[qi][2][r], sacc[qi][3][r]));
                mx[r] = rowmax16(v0);
            }
            bool defer = true;
            #pragma unroll
            for (int r = 0; r < 4; ++r)
                defer = defer && (mx[r] <= mrun[qi][r] + RESCALE_THR);
            if (__all(defer)) {
                // max stable: keep old m, skip alpha + O-rescale entirely (P <= 2^THR)
                float rsum[4] = {0.f, 0.f, 0.f, 0.f};
                #pragma unroll
                for (int nt = 0; nt < 4; ++nt)
                    #pragma unroll
                    for (int r = 0; r < 4; ++r) {
                        float p = __builtin_amdgcn_exp2f(sacc[qi][nt][r] - mrun[qi][r]);
                        sacc[qi][nt][r] = p;
                        rsum[r] += p;
                    }
                #pragma unroll
                for (int r = 0; r < 4; ++r) lrun[qi][r] += rowsum16(rsum[r]);
            } else {
                float alpha[4], mnew[4], rsum[4];
                #pragma unroll
                for (int r = 0; r < 4; ++r) {
                    mnew[r] = fmaxf(mrun[qi][r], mx[r]);
                    alpha[r] = __builtin_amdgcn_exp2f(mrun[qi][r] - mnew[r]);
                    rsum[r] = 0.f;
                }
                #pragma unroll
                for (int nt = 0; nt < 4; ++nt)
                    #pragma unroll
                    for (int r = 0; r < 4; ++r) {
                        float p = __builtin_amdgcn_exp2f(sacc[qi][nt][r] - mnew[r]);
                        sacc[qi][nt][r] = p;
                        rsum[r] += p;
                    }
                #pragma unroll
                for (int r = 0; r < 4; ++r) {
                    lrun[qi][r] = lrun[qi][r] * alpha[r] + rowsum16(rsum[r]);
                    mrun[qi][r] = mnew[r];
                }
                #pragma unroll
                for (int i = 0; i < 8; ++i)
                    #pragma unroll
                    for (int r = 0; r < 4; ++r) oacc[qi][i][r] *= alpha[r];
            }

            // ---- P: C-layout -> LDS (per-wave region, stride 136, no barrier) ----
            #pragma unroll
            for (int nt = 0; nt < 4; ++nt)
                #pragma unroll
                for (int r = 0; r < 4; ++r) {
                    int row = quad * 4 + r;
                    *(bf16*)(pb + row * 136 + nt * 32 + l16 * 2) = (bf16)sacc[qi][nt][r];
                }
            // read back this qi's A-fragments before region reuse (same-wave DS is in-order)
            #pragma unroll
            for (int ks = 0; ks < 2; ++ks)
                pf[qi][ks] = *(const bf16x8*)(pb + l16 * 136 + (ks * 4 + quad) * 16);
        }

        // ---- PV ----
        __builtin_amdgcn_s_setprio(1);
        #pragma unroll
        for (int dht = 0; dht < 8; ++dht) {
            #pragma unroll
            for (int ks = 0; ks < 2; ++ks) {
                bf16x8 vf = *(const bf16x8*)(Vsh + (dht * 16 + l16) * 128 + swz(ks * 4 + quad, l16) * 16);
                oacc[0][dht] = __builtin_amdgcn_mfma_f32_16x16x32_bf16(pf[0][ks], vf, oacc[0][dht], 0, 0, 0);
                oacc[1][dht] = __builtin_amdgcn_mfma_f32_16x16x32_bf16(pf[1][ks], vf, oacc[1][dht], 0, 0, 0);
            }
        }
        __builtin_amdgcn_s_setprio(0);

        // drains vmcnt(0) (prefetch landed) + syncs all waves before buffer swap
        __syncthreads();
    }

    #pragma unroll
    for (int qi = 0; qi < 2; ++qi)
        #pragma unroll
        for (int dht = 0; dht < 8; ++dht)
            #pragma unroll
            for (int r = 0; r < 4; ++r) {
                int s = s0 + qi * 16 + quad * 4 + r;
                float v = oacc[qi][dht][r] / lrun[qi][r];
                ab[((size_t)(b * 2048 + s)) * 2048 + h * 128 + dht * 16 + l16] = (bf16)v;
            }
}

// ---------------- launch ----------------
extern "C" void kernel_launch(void* const* d_in, const int* in_sizes, int n_in,
                              void* d_out, int out_size, void* d_ws, size_t ws_size,
                              hipStream_t stream) {
    const float* x        = (const float*)d_in[0];
    const float* cached_k = (const float*)d_in[1];
    const float* cached_v = (const float*)d_in[2];
    const float* W_q      = (const float*)d_in[3];
    const float* W_k      = (const float*)d_in[4];
    const float* W_v      = (const float*)d_in[5];
    const float* W_o      = (const float*)d_in[6];

    float* out  = (float*)d_out;
    float* kout = out + 8388608;
    float* vout = out + 25165824;

    char* ws = (char*)d_ws;
    size_t off = 0;
    auto alloc = [&](size_t elts) { bf16* p = (bf16*)(ws + off); off += elts * 2; return p; };
    bf16* xb  = alloc(8388608);
    bf16* wqb = alloc(4194304);
    bf16* wkb = alloc(4194304);
    bf16* wvb = alloc(4194304);
    bf16* wob = alloc(4194304);
    bf16* qb  = alloc(8388608);
    bf16* kb  = alloc(16777216);
    bf16* vtb = alloc(16777216);
    bf16* ab  = alloc(8388608);

    conv_bf16<<<8192, 256, 0, stream>>>(x, xb, 2097152);
    conv_bf16<<<4096, 256, 0, stream>>>(W_q, wqb, 1048576);
    conv_bf16<<<4096, 256, 0, stream>>>(W_k, wkb, 1048576);
    conv_bf16<<<4096, 256, 0, stream>>>(W_v, wvb, 1048576);
    conv_bf16<<<4096, 256, 0, stream>>>(W_o, wob, 1048576);
    copy_cache_k<<<8192, 256, 0, stream>>>(cached_k, kout, kb);
    copy_cache_v<<<dim3(64, 4, 32), dim3(32, 8), 0, stream>>>(cached_v, vout, vtb);

    gemm_nt<1><<<dim3(16, 32), 256, 0, stream>>>(xb, wqb, nullptr, qb);
    gemm_nt<2><<<dim3(16, 32), 256, 0, stream>>>(xb, wkb, kout, kb);
    gemm_nt<3><<<dim3(16, 32), 256, 0, stream>>>(xb, wvb, vout, vtb);

    flash_attn<<<512, 256, 0, stream>>>(qb, kb, vtb, ab);

    gemm_nt<0><<<dim3(16, 32), 256, 0, stream>>>(ab, wob, out, nullptr);
}

// Round 2
// 655.024 us; speedup vs baseline: 1.2411x; 1.1191x over previous
//
#include <hip/hip_runtime.h>

typedef __bf16 bf16;
typedef __bf16 bf16x4 __attribute__((ext_vector_type(4)));
typedef __bf16 bf16x8 __attribute__((ext_vector_type(8)));
typedef float f32x4 __attribute__((ext_vector_type(4)));
typedef float f32x16 __attribute__((ext_vector_type(16)));
typedef int iv2 __attribute__((ext_vector_type(2)));

#define LOG2E 1.44269504088896340736f
// 1/sqrt(128) * log2(e), folded into Q at projection time -> softmax runs in log2 domain
#define QSCALE 0.12751884935f
// defer-max threshold (log2 domain): skip O-rescale while max grows <= 8 -> P <= 256
#define RESCALE_THR 8.0f

// ---------------- async global->LDS (width 16) ----------------
__device__ __forceinline__ void gload_lds16(const void* gp, void* lp) {
    __builtin_amdgcn_global_load_lds(
        (__attribute__((address_space(1))) void*)gp,
        (__attribute__((address_space(3))) void*)lp,
        16, 0, 0);
}

// XOR swizzle of 16B-chunk index within a row (low 3 bits), self-inverse.
__device__ __forceinline__ int swz(int j, int row) {
    return (j & 8) | ((j ^ row) & 7);
}

// v_cvt_pk_bf16_f32: pack two f32 -> one u32 of 2 bf16 (no builtin on gfx950)
__device__ __forceinline__ unsigned cvtpk(float lo, float hi) {
    unsigned w;
    asm("v_cvt_pk_bf16_f32 %0, %1, %2" : "=v"(w) : "v"(lo), "v"(hi));
    return w;
}

// permlane32_swap: d_new = {d[0:31], s[0:31]}, s_new = {d[32:63], s[32:63]}
__device__ __forceinline__ iv2 permswap(unsigned a, unsigned b) {
    return __builtin_amdgcn_permlane32_swap((int)a, (int)b, false, false);
}
// combine value across lane-halves (lanes l and l+32), max / add
__device__ __forceinline__ float halfmax(float v) {
    iv2 r = permswap(__float_as_uint(v), __float_as_uint(v));
    return fmaxf(__int_as_float(r[0]), __int_as_float(r[1]));
}
__device__ __forceinline__ float halfadd(float v) {
    iv2 r = permswap(__float_as_uint(v), __float_as_uint(v));
    return __int_as_float(r[0]) + __int_as_float(r[1]);
}

// tree max / sum over two f32x16 (31 ops, depth ~5)
__device__ __forceinline__ float vmax32(const f32x16& a, const f32x16& b) {
    float t[8];
    #pragma unroll
    for (int i = 0; i < 8; ++i)
        t[i] = fmaxf(fmaxf(a[i], a[i + 8]), fmaxf(b[i], b[i + 8]));
    return fmaxf(fmaxf(fmaxf(t[0], t[1]), fmaxf(t[2], t[3])),
                 fmaxf(fmaxf(t[4], t[5]), fmaxf(t[6], t[7])));
}
__device__ __forceinline__ float vsum32(const f32x16& a, const f32x16& b) {
    float t[8];
    #pragma unroll
    for (int i = 0; i < 8; ++i)
        t[i] = (a[i] + a[i + 8]) + (b[i] + b[i + 8]);
    return ((t[0] + t[1]) + (t[2] + t[3])) + ((t[4] + t[5]) + (t[6] + t[7]));
}

// ---------------- fp32 -> bf16 convert ----------------
__global__ void conv_bf16(const float* __restrict__ in, bf16* __restrict__ out, int n4) {
    int i = blockIdx.x * 256 + threadIdx.x;
    if (i < n4) {
        float4 f = ((const float4*)in)[i];
        bf16x4 v;
        v[0] = (bf16)f.x; v[1] = (bf16)f.y; v[2] = (bf16)f.z; v[3] = (bf16)f.w;
        *(bf16x4*)(out + (size_t)i * 4) = v;
    }
}

// ---------------- cached_k -> d_out(k, t<2048) fp32 + kb bf16 ----------------
__global__ void copy_cache_k(const float* __restrict__ ck, float* __restrict__ kout,
                             bf16* __restrict__ kb) {
    size_t i = ((size_t)blockIdx.x * 256 + threadIdx.x) * 4;
    size_t bh  = i >> 18;
    size_t rem = i & 262143;
    size_t o   = (bh << 19) + rem;
    float4 f = *(const float4*)(ck + i);
    *(float4*)(kout + o) = f;
    bf16x4 v;
    v[0] = (bf16)f.x; v[1] = (bf16)f.y; v[2] = (bf16)f.z; v[3] = (bf16)f.w;
    *(bf16x4*)(kb + o) = v;
}

// ---------------- cached_v -> d_out(v, t<2048) fp32 + vtb bf16 transposed ----------------
__global__ void copy_cache_v(const float* __restrict__ cv, float* __restrict__ vout,
                             bf16* __restrict__ vtb) {
    __shared__ float tile[32][33];
    int bh = blockIdx.z;
    int t0 = blockIdx.x * 32;
    int dh0 = blockIdx.y * 32;
    int tx = threadIdx.x, ty = threadIdx.y;
    const float* src = cv + (size_t)bh * 2048 * 128;
    float* dstf = vout + (size_t)bh * 4096 * 128;
    #pragma unroll
    for (int i = 0; i < 4; ++i) {
        int t = t0 + ty * 4 + i;
        float val = src[(size_t)t * 128 + dh0 + tx];
        dstf[(size_t)t * 128 + dh0 + tx] = val;
        tile[ty * 4 + i][tx] = val;
    }
    __syncthreads();
    bf16* dstb = vtb + (size_t)bh * 128 * 4096;
    #pragma unroll
    for (int i = 0; i < 4; ++i) {
        int dh = dh0 + ty * 4 + i;
        dstb[(size_t)dh * 4096 + t0 + tx] = (bf16)tile[tx][ty * 4 + i];
    }
}

// ---------------- NT GEMM: C[M,N] = A[M,K] * B[N,K]^T, bf16 in, fp32 acc ----------------
// 2-phase double-buffered: STAGE(next) -> compute(cur) -> __syncthreads (implicit vmcnt(0))
template <int MODE>
__global__ __launch_bounds__(256)
void gemm_nt(const bf16* __restrict__ A, const bf16* __restrict__ Bm,
             float* __restrict__ out_f32, bf16* __restrict__ out_bf16) {
    const int K = 2048, N = 2048;
    __shared__ __align__(16) char smem[32768];  // 2 x (A 8K + B 8K)
    const int tid = threadIdx.x;
    const int wid = tid >> 6;
    const int lane = tid & 63;
    const int quad = lane >> 4;
    const int l16 = lane & 15;
    const int m0 = blockIdx.y * 128;
    const int n0 = blockIdx.x * 128;
    const int wm = (wid & 1) * 64;
    const int wn = (wid >> 1) * 64;

    f32x4 zero = {0.f, 0.f, 0.f, 0.f};
    f32x4 acc[4][4];
    #pragma unroll
    for (int i = 0; i < 4; ++i)
        #pragma unroll
        for (int j = 0; j < 4; ++j) acc[i][j] = zero;

    auto stage = [&](int k0, int buf) {
        char* base = smem + buf * 16384;
        #pragma unroll
        for (int t = 0; t < 2; ++t) {
            int c = t * 256 + tid;
            int row = c >> 2, kc = c & 3;
            const char* gA = (const char*)(A + (size_t)(m0 + row) * K + k0 + kc * 8);
            const char* gB = (const char*)(Bm + (size_t)(n0 + row) * K + k0 + kc * 8);
            char* lA = base + (size_t)(t * 256 + (tid & ~63)) * 16;
            char* lB = base + 8192 + (size_t)(t * 256 + (tid & ~63)) * 16;
            gload_lds16(gA, lA);
            gload_lds16(gB, lB);
        }
    };

    stage(0, 0);
    __syncthreads();

    for (int k0 = 0; k0 < K; k0 += 32) {
        const int cur = (k0 >> 5) & 1;
        if (k0 + 32 < K) stage(k0 + 32, cur ^ 1);
        const char* base = smem + cur * 16384;
        bf16x8 af[4], bfv[4];
        #pragma unroll
        for (int i = 0; i < 4; ++i) {
            af[i]  = *(const bf16x8*)(base + ((wm + i * 16 + l16) * 32 + quad * 8) * 2);
            bfv[i] = *(const bf16x8*)(base + 8192 + ((wn + i * 16 + l16) * 32 + quad * 8) * 2);
        }
        __builtin_amdgcn_s_setprio(1);
        #pragma unroll
        for (int i = 0; i < 4; ++i)
            #pragma unroll
            for (int j = 0; j < 4; ++j)
                acc[i][j] = __builtin_amdgcn_mfma_f32_16x16x32_bf16(af[i], bfv[j], acc[i][j], 0, 0, 0);
        __builtin_amdgcn_s_setprio(0);
        __syncthreads();  // drains vmcnt(0): next buffer ready; all waves done with cur
    }

    #pragma unroll
    for (int i = 0; i < 4; ++i)
        #pragma unroll
        for (int j = 0; j < 4; ++j)
            #pragma unroll
            for (int r = 0; r < 4; ++r) {
                int grow = m0 + wm + i * 16 + quad * 4 + r;
                int gcol = n0 + wn + j * 16 + l16;
                float v = acc[i][j][r];
                if (MODE == 0) {
                    out_f32[(size_t)grow * N + gcol] = v;
                } else {
                    int b = grow >> 11, s = grow & 2047;
                    int h = gcol >> 7, dh = gcol & 127;
                    if (MODE == 1) {
                        out_bf16[(((size_t)(b * 16 + h) * 2048) + s) * 128 + dh] = (bf16)(v * QSCALE);
                    } else if (MODE == 2) {
                        size_t idx = (((size_t)(b * 16 + h) * 4096) + 2048 + s) * 128 + dh;
                        out_f32[idx] = v;
                        out_bf16[idx] = (bf16)v;
                    } else {
                        size_t idx = (((size_t)(b * 16 + h) * 4096) + 2048 + s) * 128 + dh;
                        out_f32[idx] = v;
                        out_bf16[(((size_t)(b * 16 + h) * 128) + dh) * 4096 + 2048 + s] = (bf16)v;
                    }
                }
            }
}

// ---------------- flash attention v5: swapped 32x32, in-register softmax ----------------
// qb (B,H,2048,128) bf16 PRE-SCALED; kb (B,H,4096,128); vtb (B,H,128,4096) -> ab (B,S,2048)
// QK^T = mfma_32x32x16(K,Q) -> S^T, col = q = lane&31: each lane owns one q-row in regs.
// Softmax fully in-lane (tree reduce + permlane32_swap half-combine); P -> PV B-operand via
// cvt_pk_bf16 + permlane32_swap (no LDS round-trip). PV = mfma_32x32x16(V^T, P^T) -> O^T,
// col = q = lane&31: alpha-rescale / defer / final 1/l all lane-local.
// LDS: 2 x (K 16K + V 16K) = 64K double-buffered, 2-phase prefetch -> 2 blk/CU.
__global__ __launch_bounds__(256, 2)
void flash_attn(const bf16* __restrict__ qb, const bf16* __restrict__ kb,
                const bf16* __restrict__ vtb, bf16* __restrict__ ab) {
    __shared__ __align__(16) char smem[65536];
    const int tid = threadIdx.x;
    const int wid = tid >> 6;
    const int lane = tid & 63;
    const int hh = lane >> 5;   // lane half
    const int l31 = lane & 31;  // q within wave tile / row within 32-block

    // XCD swizzle: flat = 512 blocks; same head -> same XCD
    const int flat = blockIdx.x;
    const int xcd = flat & 7;
    const int idx = flat >> 3;
    const int bh = xcd * 4 + (idx >> 4);
    const int qblk = idx & 15;
    const int b = bh >> 4, h = bh & 15;
    const int s0 = qblk * 128 + wid * 32;

    const bf16* Q  = qb  + (size_t)bh * 2048 * 128;
    const bf16* Kp = kb  + (size_t)bh * 4096 * 128;
    const bf16* Vt = vtb + (size_t)bh * 128 * 4096;

    // Q fragments (B-operand of mfma(K,Q)): col=q=lane&31, k=dh=ks*16+hh*8+j
    bf16x8 qf[8];
    #pragma unroll
    for (int ks = 0; ks < 8; ++ks)
        qf[ks] = *(const bf16x8*)(Q + (size_t)(s0 + l31) * 128 + ks * 16 + hh * 8);

    f32x16 oacc[4];  // O^T: rows dh (dhb*32 + (reg&3)+8*(reg>>2)+4*hh), col q=lane&31
    #pragma unroll
    for (int dhb = 0; dhb < 4; ++dhb)
        #pragma unroll
        for (int i = 0; i < 16; ++i) oacc[dhb][i] = 0.f;
    float mrun = -1e30f, lrun = 0.f;

    auto stage = [&](int t0, int buf) {
        char* Kb = smem + buf * 32768;
        char* Vb = Kb + 16384;
        #pragma unroll
        for (int r = 0; r < 4; ++r) {
            int kc = r * 256 + tid;
            int row = kc >> 4, p = kc & 15;
            int j = swz(p, row);
            gload_lds16(Kp + (size_t)(t0 + row) * 128 + j * 8, Kb + kc * 16);
        }
        #pragma unroll
        for (int r = 0; r < 4; ++r) {
            int vc = r * 256 + tid;
            int row = vc >> 3, p = vc & 7;
            int j = (p ^ row) & 7;
            gload_lds16(Vt + (size_t)row * 4096 + t0 + j * 8, Vb + vc * 16);
        }
    };

    stage(0, 0);
    __syncthreads();  // implicit vmcnt(0): buf0 resident

    for (int t0 = 0; t0 < 4096; t0 += 64) {
        const int cur = (t0 >> 6) & 1;
        if (t0 + 64 < 4096) stage(t0 + 64, cur ^ 1);  // prefetch under this tile's compute
        const char* Ksh = smem + cur * 32768;
        const char* Vsh = Ksh + 16384;

        // ---- QK^T: S^T[t][q], two 32-t blocks, two independent MFMA chains ----
        f32x16 sacc[2];
        #pragma unroll
        for (int i = 0; i < 16; ++i) { sacc[0][i] = 0.f; sacc[1][i] = 0.f; }
        __builtin_amdgcn_s_setprio(1);
        #pragma unroll
        for (int ks = 0; ks < 8; ++ks) {
            const int r0 = l31, r1 = 32 + l31;
            bf16x8 kf0 = *(const bf16x8*)(Ksh + r0 * 256 + swz(ks * 2 + hh, r0) * 16);
            bf16x8 kf1 = *(const bf16x8*)(Ksh + r1 * 256 + swz(ks * 2 + hh, r1) * 16);
            sacc[0] = __builtin_amdgcn_mfma_f32_32x32x16_bf16(kf0, qf[ks], sacc[0], 0, 0, 0);
            sacc[1] = __builtin_amdgcn_mfma_f32_32x32x16_bf16(kf1, qf[ks], sacc[1], 0, 0, 0);
        }
        __builtin_amdgcn_s_setprio(0);

        // ---- in-lane online softmax (log2 domain) ----
        float mx = halfmax(vmax32(sacc[0], sacc[1]));
        if (!__all(mx <= mrun + RESCALE_THR)) {
            float mnew = fmaxf(mrun, mx);
            float alpha = __builtin_amdgcn_exp2f(mrun - mnew);
            #pragma unroll
            for (int dhb = 0; dhb < 4; ++dhb)
                #pragma unroll
                for (int i = 0; i < 16; ++i) oacc[dhb][i] *= alpha;
            lrun *= alpha;
            mrun = mnew;
        }
        #pragma unroll
        for (int tb = 0; tb < 2; ++tb)
            #pragma unroll
            for (int i = 0; i < 16; ++i)
                sacc[tb][i] = __builtin_amdgcn_exp2f(sacc[tb][i] - mrun);
        lrun += halfadd(vsum32(sacc[0], sacc[1]));

        // ---- P^T -> PV B-operand frags via cvt_pk + permlane32_swap ----
        // pf[ks] element j = P^T[t = ks*16 + hh*8 + j][q = lane&31]
        bf16x8 pf[4];
        #pragma unroll
        for (int tb = 0; tb < 2; ++tb)
            #pragma unroll
            for (int ksl = 0; ksl < 2; ++ksl) {
                const int g0 = ksl * 8;
                unsigned wa0 = cvtpk(sacc[tb][g0 + 0], sacc[tb][g0 + 1]);
                unsigned wb0 = cvtpk(sacc[tb][g0 + 4], sacc[tb][g0 + 5]);
                unsigned wa1 = cvtpk(sacc[tb][g0 + 2], sacc[tb][g0 + 3]);
                unsigned wb1 = cvtpk(sacc[tb][g0 + 6], sacc[tb][g0 + 7]);
                iv2 r0 = permswap(wa0, wb0);  // -> (word0, word2)
                iv2 r1 = permswap(wa1, wb1);  // -> (word1, word3)
                union { int u[4]; bf16x8 v; } pk;
                pk.u[0] = r0[0]; pk.u[1] = r1[0]; pk.u[2] = r0[1]; pk.u[3] = r1[1];
                pf[tb * 2 + ksl] = pk.v;
            }

        // ---- PV: O^T += V^T * P^T, 4 independent chains ----
        __builtin_amdgcn_s_setprio(1);
        #pragma unroll
        for (int dhb = 0; dhb < 4; ++dhb) {
            const int row = dhb * 32 + l31;
            #pragma unroll
            for (int ks = 0; ks < 4; ++ks) {
                bf16x8 vf = *(const bf16x8*)(Vsh + row * 128 + (((ks * 2 + hh) ^ row) & 7) * 16);
                oacc[dhb] = __builtin_amdgcn_mfma_f32_32x32x16_bf16(vf, pf[ks], oacc[dhb], 0, 0, 0);
            }
        }
        __builtin_amdgcn_s_setprio(0);

        // drains vmcnt(0) (prefetch landed) + syncs all waves before buffer swap
        __syncthreads();
    }

    // ---- epilogue: divide by l (lane-local), store O^T packed 4-bf16 ----
    const float inv = 1.0f / lrun;
    const int s = s0 + l31;
    #pragma unroll
    for (int dhb = 0; dhb < 4; ++dhb)
        #pragma unroll
        for (int g = 0; g < 4; ++g) {
            bf16x4 o4;
            #pragma unroll
            for (int r = 0; r < 4; ++r) o4[r] = (bf16)(oacc[dhb][g * 4 + r] * inv);
            int dh = dhb * 32 + g * 8 + hh * 4;
            *(bf16x4*)(ab + ((size_t)(b * 2048 + s)) * 2048 + h * 128 + dh) = o4;
        }
}

// ---------------- launch ----------------
extern "C" void kernel_launch(void* const* d_in, const int* in_sizes, int n_in,
                              void* d_out, int out_size, void* d_ws, size_t ws_size,
                              hipStream_t stream) {
    const float* x        = (const float*)d_in[0];
    const float* cached_k = (const float*)d_in[1];
    const float* cached_v = (const float*)d_in[2];
    const float* W_q      = (const float*)d_in[3];
    const float* W_k      = (const float*)d_in[4];
    const float* W_v      = (const float*)d_in[5];
    const float* W_o      = (const float*)d_in[6];

    float* out  = (float*)d_out;
    float* kout = out + 8388608;
    float* vout = out + 25165824;

    char* ws = (char*)d_ws;
    size_t off = 0;
    auto alloc = [&](size_t elts) { bf16* p = (bf16*)(ws + off); off += elts * 2; return p; };
    bf16* xb  = alloc(8388608);
    bf16* wqb = alloc(4194304);
    bf16* wkb = alloc(4194304);
    bf16* wvb = alloc(4194304);
    bf16* wob = alloc(4194304);
    bf16* qb  = alloc(8388608);
    bf16* kb  = alloc(16777216);
    bf16* vtb = alloc(16777216);
    bf16* ab  = alloc(8388608);

    conv_bf16<<<8192, 256, 0, stream>>>(x, xb, 2097152);
    conv_bf16<<<4096, 256, 0, stream>>>(W_q, wqb, 1048576);
    conv_bf16<<<4096, 256, 0, stream>>>(W_k, wkb, 1048576);
    conv_bf16<<<4096, 256, 0, stream>>>(W_v, wvb, 1048576);
    conv_bf16<<<4096, 256, 0, stream>>>(W_o, wob, 1048576);
    copy_cache_k<<<8192, 256, 0, stream>>>(cached_k, kout, kb);
    copy_cache_v<<<dim3(64, 4, 32), dim3(32, 8), 0, stream>>>(cached_v, vout, vtb);

    gemm_nt<1><<<dim3(16, 32), 256, 0, stream>>>(xb, wqb, nullptr, qb);
    gemm_nt<2><<<dim3(16, 32), 256, 0, stream>>>(xb, wkb, kout, kb);
    gemm_nt<3><<<dim3(16, 32), 256, 0, stream>>>(xb, wvb, vout, vtb);

    flash_attn<<<512, 256, 0, stream>>>(qb, kb, vtb, ab);

    gemm_nt<0><<<dim3(16, 32), 256, 0, stream>>>(ab, wob, out, nullptr);
}

// Round 3
// 650.630 us; speedup vs baseline: 1.2495x; 1.0068x over previous
//
#include <hip/hip_runtime.h>

typedef __bf16 bf16;
typedef __bf16 bf16x4 __attribute__((ext_vector_type(4)));
typedef __bf16 bf16x8 __attribute__((ext_vector_type(8)));
typedef float f32x4 __attribute__((ext_vector_type(4)));
typedef float f32x16 __attribute__((ext_vector_type(16)));
typedef int iv2 __attribute__((ext_vector_type(2)));

#define LOG2E 1.44269504088896340736f
// 1/sqrt(128) * log2(e), folded into Q at projection time -> softmax runs in log2 domain
#define QSCALE 0.12751884935f
// defer-max threshold (log2 domain): skip O-rescale while max grows <= 8 -> P <= 256
#define RESCALE_THR 8.0f

// ---------------- async global->LDS (width 16) ----------------
__device__ __forceinline__ void gload_lds16(const void* gp, void* lp) {
    __builtin_amdgcn_global_load_lds(
        (__attribute__((address_space(1))) void*)gp,
        (__attribute__((address_space(3))) void*)lp,
        16, 0, 0);
}

// Row-dependent swizzle mask for 256B rows (16 x 16B chunks), self-inverse per row.
// 4-bit spread (16 slots per 16-lane group) + bit2 flip between row r and r+32 so the
// paired MFMA-chain reads hit different bank-quads.
__device__ __forceinline__ int kmask(int r) {
    return (r & 15) ^ (((r >> 5) & 1) << 2);
}

// v_cvt_pk_bf16_f32: pack two f32 -> one u32 of 2 bf16 (no builtin on gfx950)
__device__ __forceinline__ unsigned cvtpk(float lo, float hi) {
    unsigned w;
    asm("v_cvt_pk_bf16_f32 %0, %1, %2" : "=v"(w) : "v"(lo), "v"(hi));
    return w;
}

// permlane32_swap: d_new = {d[0:31], s[0:31]}, s_new = {d[32:63], s[32:63]}
__device__ __forceinline__ iv2 permswap(unsigned a, unsigned b) {
    return __builtin_amdgcn_permlane32_swap((int)a, (int)b, false, false);
}
__device__ __forceinline__ float halfmax(float v) {
    iv2 r = permswap(__float_as_uint(v), __float_as_uint(v));
    return fmaxf(__int_as_float(r[0]), __int_as_float(r[1]));
}
__device__ __forceinline__ float halfadd(float v) {
    iv2 r = permswap(__float_as_uint(v), __float_as_uint(v));
    return __int_as_float(r[0]) + __int_as_float(r[1]);
}

// tree max / sum over two f32x16 (31 ops, depth ~5)
__device__ __forceinline__ float vmax32(const f32x16& a, const f32x16& b) {
    float t[8];
    #pragma unroll
    for (int i = 0; i < 8; ++i)
        t[i] = fmaxf(fmaxf(a[i], a[i + 8]), fmaxf(b[i], b[i + 8]));
    return fmaxf(fmaxf(fmaxf(t[0], t[1]), fmaxf(t[2], t[3])),
                 fmaxf(fmaxf(t[4], t[5]), fmaxf(t[6], t[7])));
}
__device__ __forceinline__ float vsum32(const f32x16& a, const f32x16& b) {
    float t[8];
    #pragma unroll
    for (int i = 0; i < 8; ++i)
        t[i] = (a[i] + a[i + 8]) + (b[i] + b[i + 8]);
    return ((t[0] + t[1]) + (t[2] + t[3])) + ((t[4] + t[5]) + (t[6] + t[7]));
}

// ---------------- fp32 -> bf16 convert: x + 4 weights in ONE launch ----------------
// blocks [0,8192): x (2097152 float4); [8192,24576): weights, 4096 blocks each.
__global__ void conv_all(const float* __restrict__ x, const float* __restrict__ wq,
                         const float* __restrict__ wk, const float* __restrict__ wv,
                         const float* __restrict__ wo, bf16* __restrict__ xb,
                         bf16* __restrict__ wbase) {
    int id = blockIdx.x;
    const float* src;
    bf16* dst;
    int i;
    if (id < 8192) {
        src = x; dst = xb;
        i = id * 256 + threadIdx.x;
    } else {
        int w = (id - 8192) >> 12;
        src = (w == 0) ? wq : (w == 1) ? wk : (w == 2) ? wv : wo;
        dst = wbase + (size_t)w * 4194304;
        i = ((id - 8192) & 4095) * 256 + threadIdx.x;
    }
    float4 f = ((const float4*)src)[i];
    bf16x4 v;
    v[0] = (bf16)f.x; v[1] = (bf16)f.y; v[2] = (bf16)f.z; v[3] = (bf16)f.w;
    *(bf16x4*)(dst + (size_t)i * 4) = v;
}

// ---------------- cached_k -> d_out(k, t<2048) fp32 + kb bf16 ----------------
__global__ void copy_cache_k(const float* __restrict__ ck, float* __restrict__ kout,
                             bf16* __restrict__ kb) {
    size_t i = ((size_t)blockIdx.x * 256 + threadIdx.x) * 4;
    size_t bh  = i >> 18;
    size_t rem = i & 262143;
    size_t o   = (bh << 19) + rem;
    float4 f = *(const float4*)(ck + i);
    *(float4*)(kout + o) = f;
    bf16x4 v;
    v[0] = (bf16)f.x; v[1] = (bf16)f.y; v[2] = (bf16)f.z; v[3] = (bf16)f.w;
    *(bf16x4*)(kb + o) = v;
}

// ---------------- cached_v -> d_out(v, t<2048) fp32 + vtb bf16 transposed ----------------
__global__ void copy_cache_v(const float* __restrict__ cv, float* __restrict__ vout,
                             bf16* __restrict__ vtb) {
    __shared__ float tile[32][33];
    int bh = blockIdx.z;
    int t0 = blockIdx.x * 32;
    int dh0 = blockIdx.y * 32;
    int tx = threadIdx.x, ty = threadIdx.y;
    const float* src = cv + (size_t)bh * 2048 * 128;
    float* dstf = vout + (size_t)bh * 4096 * 128;
    #pragma unroll
    for (int i = 0; i < 4; ++i) {
        int t = t0 + ty * 4 + i;
        float val = src[(size_t)t * 128 + dh0 + tx];
        dstf[(size_t)t * 128 + dh0 + tx] = val;
        tile[ty * 4 + i][tx] = val;
    }
    __syncthreads();
    bf16* dstb = vtb + (size_t)bh * 128 * 4096;
    #pragma unroll
    for (int i = 0; i < 4; ++i) {
        int dh = dh0 + ty * 4 + i;
        dstb[(size_t)dh * 4096 + t0 + tx] = (bf16)tile[tx][ty * 4 + i];
    }
}

// ---------------- fused QKV NT GEMM: C[4096,6144] = xb[4096,2048] * Wqkv[6144,2048]^T ----
// 1536 blocks (6 blk/CU of work -> cross-block latency hiding), bijective XCD swizzle so
// each XCD owns 4 contiguous M-panels (A reuse in its private L2). Epilogue routes by
// column segment: [0,2048) Q (scaled), [2048,4096) K (fp32+bf16), [4096,6144) V (+transpose).
__global__ __launch_bounds__(256)
void gemm_qkv(const bf16* __restrict__ A, const bf16* __restrict__ Bm,
              float* __restrict__ kout, float* __restrict__ vout,
              bf16* __restrict__ qb, bf16* __restrict__ kb, bf16* __restrict__ vtb) {
    const int K = 2048;
    __shared__ __align__(16) char smem[32768];  // 2 x (A 8K + B 8K)
    const int tid = threadIdx.x;
    const int wid = tid >> 6;
    const int lane = tid & 63;
    const int quad = lane >> 4;
    const int l16 = lane & 15;
    // XCD swizzle (1536 % 8 == 0): wgid = xcd*192 + orig/8
    const int wg = blockIdx.x;
    const int wgid = (wg & 7) * 192 + (wg >> 3);
    const int m0 = (wgid / 48) * 128;
    const int n0 = (wgid % 48) * 128;
    const int wm = (wid & 1) * 64;
    const int wn = (wid >> 1) * 64;

    f32x4 zero = {0.f, 0.f, 0.f, 0.f};
    f32x4 acc[4][4];
    #pragma unroll
    for (int i = 0; i < 4; ++i)
        #pragma unroll
        for (int j = 0; j < 4; ++j) acc[i][j] = zero;

    auto stage = [&](int k0, int buf) {
        char* base = smem + buf * 16384;
        #pragma unroll
        for (int t = 0; t < 2; ++t) {
            int c = t * 256 + tid;
            int row = c >> 2, kc = c & 3;
            const char* gA = (const char*)(A + (size_t)(m0 + row) * K + k0 + kc * 8);
            const char* gB = (const char*)(Bm + (size_t)(n0 + row) * K + k0 + kc * 8);
            char* lA = base + (size_t)(t * 256 + (tid & ~63)) * 16;
            char* lB = base + 8192 + (size_t)(t * 256 + (tid & ~63)) * 16;
            gload_lds16(gA, lA);
            gload_lds16(gB, lB);
        }
    };

    stage(0, 0);
    __syncthreads();

    for (int k0 = 0; k0 < K; k0 += 32) {
        const int cur = (k0 >> 5) & 1;
        if (k0 + 32 < K) stage(k0 + 32, cur ^ 1);
        const char* base = smem + cur * 16384;
        bf16x8 af[4], bfv[4];
        #pragma unroll
        for (int i = 0; i < 4; ++i) {
            af[i]  = *(const bf16x8*)(base + ((wm + i * 16 + l16) * 32 + quad * 8) * 2);
            bfv[i] = *(const bf16x8*)(base + 8192 + ((wn + i * 16 + l16) * 32 + quad * 8) * 2);
        }
        __builtin_amdgcn_s_setprio(1);
        #pragma unroll
        for (int i = 0; i < 4; ++i)
            #pragma unroll
            for (int j = 0; j < 4; ++j)
                acc[i][j] = __builtin_amdgcn_mfma_f32_16x16x32_bf16(af[i], bfv[j], acc[i][j], 0, 0, 0);
        __builtin_amdgcn_s_setprio(0);
        __syncthreads();
    }

    const int seg = n0 >> 11;  // 0=Q, 1=K, 2=V (uniform per block)
    #pragma unroll
    for (int i = 0; i < 4; ++i)
        #pragma unroll
        for (int j = 0; j < 4; ++j)
            #pragma unroll
            for (int r = 0; r < 4; ++r) {
                int grow = m0 + wm + i * 16 + quad * 4 + r;
                int gcol = n0 + wn + j * 16 + l16;
                float v = acc[i][j][r];
                int b = grow >> 11, s = grow & 2047;
                int c2 = gcol & 2047;
                int h = c2 >> 7, dh = c2 & 127;
                if (seg == 0) {
                    qb[(((size_t)(b * 16 + h) * 2048) + s) * 128 + dh] = (bf16)(v * QSCALE);
                } else if (seg == 1) {
                    size_t idx = (((size_t)(b * 16 + h) * 4096) + 2048 + s) * 128 + dh;
                    kout[idx] = v;
                    kb[idx] = (bf16)v;
                } else {
                    size_t idx = (((size_t)(b * 16 + h) * 4096) + 2048 + s) * 128 + dh;
                    vout[idx] = v;
                    vtb[(((size_t)(b * 16 + h) * 128) + dh) * 4096 + 2048 + s] = (bf16)v;
                }
            }
}

// ---------------- output NT GEMM: out[4096,2048] = ab * Wo^T ----------------
__global__ __launch_bounds__(256)
void gemm_out(const bf16* __restrict__ A, const bf16* __restrict__ Bm,
              float* __restrict__ out_f32) {
    const int K = 2048, N = 2048;
    __shared__ __align__(16) char smem[32768];
    const int tid = threadIdx.x;
    const int wid = tid >> 6;
    const int lane = tid & 63;
    const int quad = lane >> 4;
    const int l16 = lane & 15;
    // XCD swizzle (512 % 8 == 0)
    const int wg = blockIdx.x;
    const int wgid = (wg & 7) * 64 + (wg >> 3);
    const int m0 = (wgid >> 4) * 128;
    const int n0 = (wgid & 15) * 128;
    const int wm = (wid & 1) * 64;
    const int wn = (wid >> 1) * 64;

    f32x4 zero = {0.f, 0.f, 0.f, 0.f};
    f32x4 acc[4][4];
    #pragma unroll
    for (int i = 0; i < 4; ++i)
        #pragma unroll
        for (int j = 0; j < 4; ++j) acc[i][j] = zero;

    auto stage = [&](int k0, int buf) {
        char* base = smem + buf * 16384;
        #pragma unroll
        for (int t = 0; t < 2; ++t) {
            int c = t * 256 + tid;
            int row = c >> 2, kc = c & 3;
            const char* gA = (const char*)(A + (size_t)(m0 + row) * K + k0 + kc * 8);
            const char* gB = (const char*)(Bm + (size_t)(n0 + row) * K + k0 + kc * 8);
            char* lA = base + (size_t)(t * 256 + (tid & ~63)) * 16;
            char* lB = base + 8192 + (size_t)(t * 256 + (tid & ~63)) * 16;
            gload_lds16(gA, lA);
            gload_lds16(gB, lB);
        }
    };

    stage(0, 0);
    __syncthreads();

    for (int k0 = 0; k0 < K; k0 += 32) {
        const int cur = (k0 >> 5) & 1;
        if (k0 + 32 < K) stage(k0 + 32, cur ^ 1);
        const char* base = smem + cur * 16384;
        bf16x8 af[4], bfv[4];
        #pragma unroll
        for (int i = 0; i < 4; ++i) {
            af[i]  = *(const bf16x8*)(base + ((wm + i * 16 + l16) * 32 + quad * 8) * 2);
            bfv[i] = *(const bf16x8*)(base + 8192 + ((wn + i * 16 + l16) * 32 + quad * 8) * 2);
        }
        __builtin_amdgcn_s_setprio(1);
        #pragma unroll
        for (int i = 0; i < 4; ++i)
            #pragma unroll
            for (int j = 0; j < 4; ++j)
                acc[i][j] = __builtin_amdgcn_mfma_f32_16x16x32_bf16(af[i], bfv[j], acc[i][j], 0, 0, 0);
        __builtin_amdgcn_s_setprio(0);
        __syncthreads();
    }

    #pragma unroll
    for (int i = 0; i < 4; ++i)
        #pragma unroll
        for (int j = 0; j < 4; ++j)
            #pragma unroll
            for (int r = 0; r < 4; ++r) {
                int grow = m0 + wm + i * 16 + quad * 4 + r;
                int gcol = n0 + wn + j * 16 + l16;
                out_f32[(size_t)grow * N + gcol] = acc[i][j][r];
            }
}

// ---------------- flash attention v6: swapped 32x32, 4-bit LDS swizzle ----------------
// qb (B,H,2048,128) bf16 PRE-SCALED; kb (B,H,4096,128); vtb (B,H,128,4096) -> ab (B,S,2048)
// v6 vs v5: K and V LDS tiles both 64 rows x 256B with mask(r) = (r&15) ^ ((r>>5)<<2):
// 16-slot spread per 16-lane read group AND the (r, r+32) paired chain reads land on
// different bank-quads. V restaged as row r = dh&63 holding dh and dh+64 halves.
__global__ __launch_bounds__(256, 2)
void flash_attn(const bf16* __restrict__ qb, const bf16* __restrict__ kb,
                const bf16* __restrict__ vtb, bf16* __restrict__ ab) {
    __shared__ __align__(16) char smem[65536];
    const int tid = threadIdx.x;
    const int wid = tid >> 6;
    const int lane = tid & 63;
    const int hh = lane >> 5;   // lane half
    const int l31 = lane & 31;  // q within wave tile / row within 32-block

    // XCD swizzle: flat = 512 blocks; same head -> same XCD
    const int flat = blockIdx.x;
    const int xcd = flat & 7;
    const int idx = flat >> 3;
    const int bh = xcd * 4 + (idx >> 4);
    const int qblk = idx & 15;
    const int b = bh >> 4, h = bh & 15;
    const int s0 = qblk * 128 + wid * 32;

    const bf16* Q  = qb  + (size_t)bh * 2048 * 128;
    const bf16* Kp = kb  + (size_t)bh * 4096 * 128;
    const bf16* Vt = vtb + (size_t)bh * 128 * 4096;

    // Q fragments (B-operand of mfma(K,Q)): col=q=lane&31, k=dh=ks*16+hh*8+j
    bf16x8 qf[8];
    #pragma unroll
    for (int ks = 0; ks < 8; ++ks)
        qf[ks] = *(const bf16x8*)(Q + (size_t)(s0 + l31) * 128 + ks * 16 + hh * 8);

    f32x16 oacc[4];  // O^T: rows dh (dhb*32 + (reg&3)+8*(reg>>2)+4*hh), col q=lane&31
    #pragma unroll
    for (int dhb = 0; dhb < 4; ++dhb)
        #pragma unroll
        for (int i = 0; i < 16; ++i) oacc[dhb][i] = 0.f;
    float mrun = -1e30f, lrun = 0.f;

    auto stage = [&](int t0, int buf) {
        char* Kb = smem + buf * 32768;
        char* Vb = Kb + 16384;
        // K: 64 rows x 256B; slot j at row holds global chunk j ^ kmask(row)
        #pragma unroll
        for (int r4 = 0; r4 < 4; ++r4) {
            int kc = r4 * 256 + tid;
            int row = kc >> 4, p = kc & 15;
            int j = p ^ kmask(row);
            gload_lds16(Kp + (size_t)(t0 + row) * 128 + j * 8, Kb + kc * 16);
        }
        // V: 64 rows x 256B; row r slot j holds chunk g = j ^ kmask(r),
        //    g = half*8 + p -> dh = r + half*64, t-chunk p
        #pragma unroll
        for (int r4 = 0; r4 < 4; ++r4) {
            int vc = r4 * 256 + tid;
            int row = vc >> 4, j = vc & 15;
            int g = j ^ kmask(row);
            int dh = row + (g >> 3) * 64;
            int p = g & 7;
            gload_lds16(Vt + (size_t)dh * 4096 + t0 + p * 8, Vb + vc * 16);
        }
    };

    stage(0, 0);
    __syncthreads();  // implicit vmcnt(0): buf0 resident

    for (int t0 = 0; t0 < 4096; t0 += 64) {
        const int cur = (t0 >> 6) & 1;
        if (t0 + 64 < 4096) stage(t0 + 64, cur ^ 1);  // prefetch under this tile's compute
        const char* Ksh = smem + cur * 32768;
        const char* Vsh = Ksh + 16384;

        // ---- QK^T: S^T[t][q], two 32-t blocks, two independent MFMA chains ----
        f32x16 sacc[2];
        #pragma unroll
        for (int i = 0; i < 16; ++i) { sacc[0][i] = 0.f; sacc[1][i] = 0.f; }
        __builtin_amdgcn_s_setprio(1);
        #pragma unroll
        for (int ks = 0; ks < 8; ++ks) {
            const int c = ks * 2 + hh;
            const int r0 = l31, r1 = 32 + l31;
            bf16x8 kf0 = *(const bf16x8*)(Ksh + r0 * 256 + (c ^ kmask(r0)) * 16);
            bf16x8 kf1 = *(const bf16x8*)(Ksh + r1 * 256 + (c ^ kmask(r1)) * 16);
            sacc[0] = __builtin_amdgcn_mfma_f32_32x32x16_bf16(kf0, qf[ks], sacc[0], 0, 0, 0);
            sacc[1] = __builtin_amdgcn_mfma_f32_32x32x16_bf16(kf1, qf[ks], sacc[1], 0, 0, 0);
        }
        __builtin_amdgcn_s_setprio(0);

        // ---- in-lane online softmax (log2 domain) ----
        float mx = halfmax(vmax32(sacc[0], sacc[1]));
        if (!__all(mx <= mrun + RESCALE_THR)) {
            float mnew = fmaxf(mrun, mx);
            float alpha = __builtin_amdgcn_exp2f(mrun - mnew);
            #pragma unroll
            for (int dhb = 0; dhb < 4; ++dhb)
                #pragma unroll
                for (int i = 0; i < 16; ++i) oacc[dhb][i] *= alpha;
            lrun *= alpha;
            mrun = mnew;
        }
        #pragma unroll
        for (int tb = 0; tb < 2; ++tb)
            #pragma unroll
            for (int i = 0; i < 16; ++i)
                sacc[tb][i] = __builtin_amdgcn_exp2f(sacc[tb][i] - mrun);
        lrun += halfadd(vsum32(sacc[0], sacc[1]));

        // ---- P^T -> PV B-operand frags via cvt_pk + permlane32_swap ----
        bf16x8 pf[4];
        #pragma unroll
        for (int tb = 0; tb < 2; ++tb)
            #pragma unroll
            for (int ksl = 0; ksl < 2; ++ksl) {
                const int g0 = ksl * 8;
                unsigned wa0 = cvtpk(sacc[tb][g0 + 0], sacc[tb][g0 + 1]);
                unsigned wb0 = cvtpk(sacc[tb][g0 + 4], sacc[tb][g0 + 5]);
                unsigned wa1 = cvtpk(sacc[tb][g0 + 2], sacc[tb][g0 + 3]);
                unsigned wb1 = cvtpk(sacc[tb][g0 + 6], sacc[tb][g0 + 7]);
                iv2 r0 = permswap(wa0, wb0);  // -> (word0, word2)
                iv2 r1 = permswap(wa1, wb1);  // -> (word1, word3)
                union { int u[4]; bf16x8 v; } pk;
                pk.u[0] = r0[0]; pk.u[1] = r1[0]; pk.u[2] = r0[1]; pk.u[3] = r1[1];
                pf[tb * 2 + ksl] = pk.v;
            }

        // ---- PV: O^T += V^T * P^T, 4 independent chains ----
        __builtin_amdgcn_s_setprio(1);
        #pragma unroll
        for (int dhb = 0; dhb < 4; ++dhb) {
            const int rr = ((dhb & 1) << 5) + l31;  // LDS row (dh & 63)
            #pragma unroll
            for (int ks = 0; ks < 4; ++ks) {
                const int g = (dhb >> 1) * 8 + ks * 2 + hh;  // half*8 + t-chunk
                bf16x8 vf = *(const bf16x8*)(Vsh + rr * 256 + (g ^ kmask(rr)) * 16);
                oacc[dhb] = __builtin_amdgcn_mfma_f32_32x32x16_bf16(vf, pf[ks], oacc[dhb], 0, 0, 0);
            }
        }
        __builtin_amdgcn_s_setprio(0);

        // drains vmcnt(0) (prefetch landed) + syncs all waves before buffer swap
        __syncthreads();
    }

    // ---- epilogue: divide by l (lane-local), store O^T packed 4-bf16 ----
    const float inv = 1.0f / lrun;
    const int s = s0 + l31;
    #pragma unroll
    for (int dhb = 0; dhb < 4; ++dhb)
        #pragma unroll
        for (int g = 0; g < 4; ++g) {
            bf16x4 o4;
            #pragma unroll
            for (int r = 0; r < 4; ++r) o4[r] = (bf16)(oacc[dhb][g * 4 + r] * inv);
            int dh = dhb * 32 + g * 8 + hh * 4;
            *(bf16x4*)(ab + ((size_t)(b * 2048 + s)) * 2048 + h * 128 + dh) = o4;
        }
}

// ---------------- launch ----------------
extern "C" void kernel_launch(void* const* d_in, const int* in_sizes, int n_in,
                              void* d_out, int out_size, void* d_ws, size_t ws_size,
                              hipStream_t stream) {
    const float* x        = (const float*)d_in[0];
    const float* cached_k = (const float*)d_in[1];
    const float* cached_v = (const float*)d_in[2];
    const float* W_q      = (const float*)d_in[3];
    const float* W_k      = (const float*)d_in[4];
    const float* W_v      = (const float*)d_in[5];
    const float* W_o      = (const float*)d_in[6];

    float* out  = (float*)d_out;
    float* kout = out + 8388608;
    float* vout = out + 25165824;

    char* ws = (char*)d_ws;
    size_t off = 0;
    auto alloc = [&](size_t elts) { bf16* p = (bf16*)(ws + off); off += elts * 2; return p; };
    bf16* xb  = alloc(8388608);
    bf16* wqb = alloc(4194304);   // wqb/wkb/wvb contiguous => B[6144,2048] for fused QKV
    bf16* wkb = alloc(4194304);
    bf16* wvb = alloc(4194304);
    bf16* wob = alloc(4194304);
    bf16* qb  = alloc(8388608);
    bf16* kb  = alloc(16777216);
    bf16* vtb = alloc(16777216);
    bf16* ab  = alloc(8388608);
    (void)wkb; (void)wvb;

    conv_all<<<24576, 256, 0, stream>>>(x, W_q, W_k, W_v, W_o, xb, wqb);
    copy_cache_k<<<8192, 256, 0, stream>>>(cached_k, kout, kb);
    copy_cache_v<<<dim3(64, 4, 32), dim3(32, 8), 0, stream>>>(cached_v, vout, vtb);

    gemm_qkv<<<1536, 256, 0, stream>>>(xb, wqb, kout, vout, qb, kb, vtb);

    flash_attn<<<512, 256, 0, stream>>>(qb, kb, vtb, ab);

    gemm_out<<<512, 256, 0, stream>>>(ab, wob, out);
}

// Round 4
// 641.968 us; speedup vs baseline: 1.2664x; 1.0135x over previous
//
#include <hip/hip_runtime.h>

typedef __bf16 bf16;
typedef __bf16 bf16x4 __attribute__((ext_vector_type(4)));
typedef __bf16 bf16x8 __attribute__((ext_vector_type(8)));
typedef float f32x4 __attribute__((ext_vector_type(4)));
typedef float f32x16 __attribute__((ext_vector_type(16)));
typedef int iv2 __attribute__((ext_vector_type(2)));

#define LOG2E 1.44269504088896340736f
// 1/sqrt(128) * log2(e), folded into Q at projection time -> softmax runs in log2 domain
#define QSCALE 0.12751884935f
// defer-max threshold (log2 domain): skip O-rescale while max grows <= 8 -> P <= 256
#define RESCALE_THR 8.0f

// ---------------- async global->LDS (width 16) ----------------
__device__ __forceinline__ void gload_lds16(const void* gp, void* lp) {
    __builtin_amdgcn_global_load_lds(
        (__attribute__((address_space(1))) void*)gp,
        (__attribute__((address_space(3))) void*)lp,
        16, 0, 0);
}

// Row-dependent swizzle mask for 256B rows (16 x 16B chunks), self-inverse per row.
__device__ __forceinline__ int kmask(int r) {
    return (r & 15) ^ (((r >> 5) & 1) << 2);
}

// v_cvt_pk_bf16_f32: pack two f32 -> one u32 of 2 bf16 (no builtin on gfx950)
__device__ __forceinline__ unsigned cvtpk(float lo, float hi) {
    unsigned w;
    asm("v_cvt_pk_bf16_f32 %0, %1, %2" : "=v"(w) : "v"(lo), "v"(hi));
    return w;
}

// permlane32_swap: d_new = {d[0:31], s[0:31]}, s_new = {d[32:63], s[32:63]}
__device__ __forceinline__ iv2 permswap(unsigned a, unsigned b) {
    return __builtin_amdgcn_permlane32_swap((int)a, (int)b, false, false);
}
__device__ __forceinline__ float halfmax(float v) {
    iv2 r = permswap(__float_as_uint(v), __float_as_uint(v));
    return fmaxf(__int_as_float(r[0]), __int_as_float(r[1]));
}
__device__ __forceinline__ float halfadd(float v) {
    iv2 r = permswap(__float_as_uint(v), __float_as_uint(v));
    return __int_as_float(r[0]) + __int_as_float(r[1]);
}

// tree max / sum over two f32x16 (31 ops, depth ~5)
__device__ __forceinline__ float vmax32(const f32x16& a, const f32x16& b) {
    float t[8];
    #pragma unroll
    for (int i = 0; i < 8; ++i)
        t[i] = fmaxf(fmaxf(a[i], a[i + 8]), fmaxf(b[i], b[i + 8]));
    return fmaxf(fmaxf(fmaxf(t[0], t[1]), fmaxf(t[2], t[3])),
                 fmaxf(fmaxf(t[4], t[5]), fmaxf(t[6], t[7])));
}
__device__ __forceinline__ float vsum32(const f32x16& a, const f32x16& b) {
    float t[8];
    #pragma unroll
    for (int i = 0; i < 8; ++i)
        t[i] = (a[i] + a[i + 8]) + (b[i] + b[i + 8]);
    return ((t[0] + t[1]) + (t[2] + t[3])) + ((t[4] + t[5]) + (t[6] + t[7]));
}

// ---------------- fp32 -> bf16 convert: x + 4 weights in ONE launch ----------------
__global__ void conv_all(const float* __restrict__ x, const float* __restrict__ wq,
                         const float* __restrict__ wk, const float* __restrict__ wv,
                         const float* __restrict__ wo, bf16* __restrict__ xb,
                         bf16* __restrict__ wbase) {
    int id = blockIdx.x;
    const float* src;
    bf16* dst;
    int i;
    if (id < 8192) {
        src = x; dst = xb;
        i = id * 256 + threadIdx.x;
    } else {
        int w = (id - 8192) >> 12;
        src = (w == 0) ? wq : (w == 1) ? wk : (w == 2) ? wv : wo;
        dst = wbase + (size_t)w * 4194304;
        i = ((id - 8192) & 4095) * 256 + threadIdx.x;
    }
    float4 f = ((const float4*)src)[i];
    bf16x4 v;
    v[0] = (bf16)f.x; v[1] = (bf16)f.y; v[2] = (bf16)f.z; v[3] = (bf16)f.w;
    *(bf16x4*)(dst + (size_t)i * 4) = v;
}

// ---------------- cached_k -> d_out(k, t<2048) fp32 + kb bf16 ----------------
__global__ void copy_cache_k(const float* __restrict__ ck, float* __restrict__ kout,
                             bf16* __restrict__ kb) {
    size_t i = ((size_t)blockIdx.x * 256 + threadIdx.x) * 4;
    size_t bh  = i >> 18;
    size_t rem = i & 262143;
    size_t o   = (bh << 19) + rem;
    float4 f = *(const float4*)(ck + i);
    *(float4*)(kout + o) = f;
    bf16x4 v;
    v[0] = (bf16)f.x; v[1] = (bf16)f.y; v[2] = (bf16)f.z; v[3] = (bf16)f.w;
    *(bf16x4*)(kb + o) = v;
}

// ---------------- cached_v -> d_out(v, t<2048) fp32 + vtb bf16 transposed ----------------
__global__ void copy_cache_v(const float* __restrict__ cv, float* __restrict__ vout,
                             bf16* __restrict__ vtb) {
    __shared__ float tile[32][33];
    int bh = blockIdx.z;
    int t0 = blockIdx.x * 32;
    int dh0 = blockIdx.y * 32;
    int tx = threadIdx.x, ty = threadIdx.y;
    const float* src = cv + (size_t)bh * 2048 * 128;
    float* dstf = vout + (size_t)bh * 4096 * 128;
    #pragma unroll
    for (int i = 0; i < 4; ++i) {
        int t = t0 + ty * 4 + i;
        float val = src[(size_t)t * 128 + dh0 + tx];
        dstf[(size_t)t * 128 + dh0 + tx] = val;
        tile[ty * 4 + i][tx] = val;
    }
    __syncthreads();
    bf16* dstb = vtb + (size_t)bh * 128 * 4096;
    #pragma unroll
    for (int i = 0; i < 4; ++i) {
        int dh = dh0 + ty * 4 + i;
        dstb[(size_t)dh * 4096 + t0 + tx] = (bf16)tile[tx][ty * 4 + i];
    }
}

// ---------------- vout(t in [2048,4096)) fp32 -> vtb bf16 transposed ----------------
// Runs AFTER gemm_qkv (which writes vout dense); removes the 8KB-stride 2B scatter
// from the GEMM epilogue. Same proven transpose pattern as copy_cache_v.
__global__ void transpose_vnew(const float* __restrict__ vout, bf16* __restrict__ vtb) {
    __shared__ float tile[32][33];
    int bh = blockIdx.z;
    int t0 = 2048 + blockIdx.x * 32;
    int dh0 = blockIdx.y * 32;
    int tx = threadIdx.x, ty = threadIdx.y;
    const float* src = vout + (size_t)bh * 4096 * 128;
    #pragma unroll
    for (int i = 0; i < 4; ++i) {
        int t = t0 + ty * 4 + i;
        tile[ty * 4 + i][tx] = src[(size_t)t * 128 + dh0 + tx];
    }
    __syncthreads();
    bf16* dstb = vtb + (size_t)bh * 128 * 4096;
    #pragma unroll
    for (int i = 0; i < 4; ++i) {
        int dh = dh0 + ty * 4 + i;
        dstb[(size_t)dh * 4096 + t0 + tx] = (bf16)tile[tx][ty * 4 + i];
    }
}

// ---------------- fused QKV NT GEMM: C[4096,6144] = xb[4096,2048] * Wqkv[6144,2048]^T ----
// XCD N-partition: each XCD owns 6 n-panels (3 MB of B, resident in its 4 MB L2 for the
// whole kernel), m-outer sweep so the A panel is reused 6x back-to-back and A dedups
// across XCDs via L3 (all XCDs sweep m in lockstep). Epilogue routes by column segment:
// [0,2048) Q (scaled bf16), [2048,4096) K (fp32+bf16 dense), [4096,6144) V (fp32 dense;
// transpose done by transpose_vnew afterwards).
__global__ __launch_bounds__(256)
void gemm_qkv(const bf16* __restrict__ A, const bf16* __restrict__ Bm,
              float* __restrict__ kout, float* __restrict__ vout,
              bf16* __restrict__ qb, bf16* __restrict__ kb) {
    const int K = 2048;
    __shared__ __align__(16) char smem[32768];  // 2 x (A 8K + B 8K)
    const int tid = threadIdx.x;
    const int wid = tid >> 6;
    const int lane = tid & 63;
    const int quad = lane >> 4;
    const int l16 = lane & 15;
    // N-split XCD map: xcd owns n-panels [6*xcd, 6*xcd+6); m-outer, n-inner.
    const int wg = blockIdx.x;
    const int xcd = wg & 7;
    const int i_x = wg >> 3;           // 0..191
    const int m0 = (i_x / 6) * 128;    // 0..31 panels
    const int n0 = (xcd * 6 + i_x % 6) * 128;  // 0..47 panels
    const int wm = (wid & 1) * 64;
    const int wn = (wid >> 1) * 64;

    f32x4 zero = {0.f, 0.f, 0.f, 0.f};
    f32x4 acc[4][4];
    #pragma unroll
    for (int i = 0; i < 4; ++i)
        #pragma unroll
        for (int j = 0; j < 4; ++j) acc[i][j] = zero;

    auto stage = [&](int k0, int buf) {
        char* base = smem + buf * 16384;
        #pragma unroll
        for (int t = 0; t < 2; ++t) {
            int c = t * 256 + tid;
            int row = c >> 2, kc = c & 3;
            const char* gA = (const char*)(A + (size_t)(m0 + row) * K + k0 + kc * 8);
            const char* gB = (const char*)(Bm + (size_t)(n0 + row) * K + k0 + kc * 8);
            char* lA = smem + buf * 16384 + (size_t)(t * 256 + (tid & ~63)) * 16;
            char* lB = base + 8192 + (size_t)(t * 256 + (tid & ~63)) * 16;
            gload_lds16(gA, lA);
            gload_lds16(gB, lB);
        }
    };

    stage(0, 0);
    __syncthreads();

    for (int k0 = 0; k0 < K; k0 += 32) {
        const int cur = (k0 >> 5) & 1;
        if (k0 + 32 < K) stage(k0 + 32, cur ^ 1);
        const char* base = smem + cur * 16384;
        bf16x8 af[4], bfv[4];
        #pragma unroll
        for (int i = 0; i < 4; ++i) {
            af[i]  = *(const bf16x8*)(base + ((wm + i * 16 + l16) * 32 + quad * 8) * 2);
            bfv[i] = *(const bf16x8*)(base + 8192 + ((wn + i * 16 + l16) * 32 + quad * 8) * 2);
        }
        __builtin_amdgcn_s_setprio(1);
        #pragma unroll
        for (int i = 0; i < 4; ++i)
            #pragma unroll
            for (int j = 0; j < 4; ++j)
                acc[i][j] = __builtin_amdgcn_mfma_f32_16x16x32_bf16(af[i], bfv[j], acc[i][j], 0, 0, 0);
        __builtin_amdgcn_s_setprio(0);
        __syncthreads();
    }

    const int seg = n0 >> 11;  // 0=Q, 1=K, 2=V (uniform per block)
    #pragma unroll
    for (int i = 0; i < 4; ++i)
        #pragma unroll
        for (int j = 0; j < 4; ++j)
            #pragma unroll
            for (int r = 0; r < 4; ++r) {
                int grow = m0 + wm + i * 16 + quad * 4 + r;
                int gcol = n0 + wn + j * 16 + l16;
                float v = acc[i][j][r];
                int b = grow >> 11, s = grow & 2047;
                int c2 = gcol & 2047;
                int h = c2 >> 7, dh = c2 & 127;
                if (seg == 0) {
                    qb[(((size_t)(b * 16 + h) * 2048) + s) * 128 + dh] = (bf16)(v * QSCALE);
                } else if (seg == 1) {
                    size_t idx = (((size_t)(b * 16 + h) * 4096) + 2048 + s) * 128 + dh;
                    kout[idx] = v;
                    kb[idx] = (bf16)v;
                } else {
                    size_t idx = (((size_t)(b * 16 + h) * 4096) + 2048 + s) * 128 + dh;
                    vout[idx] = v;
                }
            }
}

// ---------------- output NT GEMM: out[4096,2048] = ab * Wo^T ----------------
// XCD N-partition: each XCD owns 2 n-panels (1 MB of B, L2-resident for the whole
// kernel) -- the deliberate version of R2's accidentally-optimal layout.
__global__ __launch_bounds__(256)
void gemm_out(const bf16* __restrict__ A, const bf16* __restrict__ Bm,
              float* __restrict__ out_f32) {
    const int K = 2048, N = 2048;
    __shared__ __align__(16) char smem[32768];
    const int tid = threadIdx.x;
    const int wid = tid >> 6;
    const int lane = tid & 63;
    const int quad = lane >> 4;
    const int l16 = lane & 15;
    const int wg = blockIdx.x;
    const int xcd = wg & 7;
    const int i_x = wg >> 3;                  // 0..63
    const int m0 = (i_x >> 1) * 128;          // 0..31 panels
    const int n0 = (xcd * 2 + (i_x & 1)) * 128;  // 0..15 panels
    const int wm = (wid & 1) * 64;
    const int wn = (wid >> 1) * 64;

    f32x4 zero = {0.f, 0.f, 0.f, 0.f};
    f32x4 acc[4][4];
    #pragma unroll
    for (int i = 0; i < 4; ++i)
        #pragma unroll
        for (int j = 0; j < 4; ++j) acc[i][j] = zero;

    auto stage = [&](int k0, int buf) {
        char* base = smem + buf * 16384;
        #pragma unroll
        for (int t = 0; t < 2; ++t) {
            int c = t * 256 + tid;
            int row = c >> 2, kc = c & 3;
            const char* gA = (const char*)(A + (size_t)(m0 + row) * K + k0 + kc * 8);
            const char* gB = (const char*)(Bm + (size_t)(n0 + row) * K + k0 + kc * 8);
            char* lA = base + (size_t)(t * 256 + (tid & ~63)) * 16;
            char* lB = base + 8192 + (size_t)(t * 256 + (tid & ~63)) * 16;
            gload_lds16(gA, lA);
            gload_lds16(gB, lB);
        }
    };

    stage(0, 0);
    __syncthreads();

    for (int k0 = 0; k0 < K; k0 += 32) {
        const int cur = (k0 >> 5) & 1;
        if (k0 + 32 < K) stage(k0 + 32, cur ^ 1);
        const char* base = smem + cur * 16384;
        bf16x8 af[4], bfv[4];
        #pragma unroll
        for (int i = 0; i < 4; ++i) {
            af[i]  = *(const bf16x8*)(base + ((wm + i * 16 + l16) * 32 + quad * 8) * 2);
            bfv[i] = *(const bf16x8*)(base + 8192 + ((wn + i * 16 + l16) * 32 + quad * 8) * 2);
        }
        __builtin_amdgcn_s_setprio(1);
        #pragma unroll
        for (int i = 0; i < 4; ++i)
            #pragma unroll
            for (int j = 0; j < 4; ++j)
                acc[i][j] = __builtin_amdgcn_mfma_f32_16x16x32_bf16(af[i], bfv[j], acc[i][j], 0, 0, 0);
        __builtin_amdgcn_s_setprio(0);
        __syncthreads();
    }

    #pragma unroll
    for (int i = 0; i < 4; ++i)
        #pragma unroll
        for (int j = 0; j < 4; ++j)
            #pragma unroll
            for (int r = 0; r < 4; ++r) {
                int grow = m0 + wm + i * 16 + quad * 4 + r;
                int gcol = n0 + wn + j * 16 + l16;
                out_f32[(size_t)grow * N + gcol] = acc[i][j][r];
            }
}

// ---------------- flash attention v6: swapped 32x32, 4-bit LDS swizzle ----------------
// qb (B,H,2048,128) bf16 PRE-SCALED; kb (B,H,4096,128); vtb (B,H,128,4096) -> ab (B,S,2048)
__global__ __launch_bounds__(256, 2)
void flash_attn(const bf16* __restrict__ qb, const bf16* __restrict__ kb,
                const bf16* __restrict__ vtb, bf16* __restrict__ ab) {
    __shared__ __align__(16) char smem[65536];
    const int tid = threadIdx.x;
    const int wid = tid >> 6;
    const int lane = tid & 63;
    const int hh = lane >> 5;   // lane half
    const int l31 = lane & 31;  // q within wave tile / row within 32-block

    // XCD swizzle: flat = 512 blocks; same head -> same XCD
    const int flat = blockIdx.x;
    const int xcd = flat & 7;
    const int idx = flat >> 3;
    const int bh = xcd * 4 + (idx >> 4);
    const int qblk = idx & 15;
    const int b = bh >> 4, h = bh & 15;
    const int s0 = qblk * 128 + wid * 32;

    const bf16* Q  = qb  + (size_t)bh * 2048 * 128;
    const bf16* Kp = kb  + (size_t)bh * 4096 * 128;
    const bf16* Vt = vtb + (size_t)bh * 128 * 4096;

    // Q fragments (B-operand of mfma(K,Q)): col=q=lane&31, k=dh=ks*16+hh*8+j
    bf16x8 qf[8];
    #pragma unroll
    for (int ks = 0; ks < 8; ++ks)
        qf[ks] = *(const bf16x8*)(Q + (size_t)(s0 + l31) * 128 + ks * 16 + hh * 8);

    f32x16 oacc[4];  // O^T: rows dh (dhb*32 + (reg&3)+8*(reg>>2)+4*hh), col q=lane&31
    #pragma unroll
    for (int dhb = 0; dhb < 4; ++dhb)
        #pragma unroll
        for (int i = 0; i < 16; ++i) oacc[dhb][i] = 0.f;
    float mrun = -1e30f, lrun = 0.f;

    auto stage = [&](int t0, int buf) {
        char* Kb = smem + buf * 32768;
        char* Vb = Kb + 16384;
        // K: 64 rows x 256B; slot j at row holds global chunk j ^ kmask(row)
        #pragma unroll
        for (int r4 = 0; r4 < 4; ++r4) {
            int kc = r4 * 256 + tid;
            int row = kc >> 4, p = kc & 15;
            int j = p ^ kmask(row);
            gload_lds16(Kp + (size_t)(t0 + row) * 128 + j * 8, Kb + kc * 16);
        }
        // V: 64 rows x 256B; row r slot j holds chunk g = j ^ kmask(r),
        //    g = half*8 + p -> dh = r + half*64, t-chunk p
        #pragma unroll
        for (int r4 = 0; r4 < 4; ++r4) {
            int vc = r4 * 256 + tid;
            int row = vc >> 4, j = vc & 15;
            int g = j ^ kmask(row);
            int dh = row + (g >> 3) * 64;
            int p = g & 7;
            gload_lds16(Vt + (size_t)dh * 4096 + t0 + p * 8, Vb + vc * 16);
        }
    };

    stage(0, 0);
    __syncthreads();  // implicit vmcnt(0): buf0 resident

    for (int t0 = 0; t0 < 4096; t0 += 64) {
        const int cur = (t0 >> 6) & 1;
        if (t0 + 64 < 4096) stage(t0 + 64, cur ^ 1);  // prefetch under this tile's compute
        const char* Ksh = smem + cur * 32768;
        const char* Vsh = Ksh + 16384;

        // ---- QK^T: S^T[t][q], two 32-t blocks, two independent MFMA chains ----
        f32x16 sacc[2];
        #pragma unroll
        for (int i = 0; i < 16; ++i) { sacc[0][i] = 0.f; sacc[1][i] = 0.f; }
        __builtin_amdgcn_s_setprio(1);
        #pragma unroll
        for (int ks = 0; ks < 8; ++ks) {
            const int c = ks * 2 + hh;
            const int r0 = l31, r1 = 32 + l31;
            bf16x8 kf0 = *(const bf16x8*)(Ksh + r0 * 256 + (c ^ kmask(r0)) * 16);
            bf16x8 kf1 = *(const bf16x8*)(Ksh + r1 * 256 + (c ^ kmask(r1)) * 16);
            sacc[0] = __builtin_amdgcn_mfma_f32_32x32x16_bf16(kf0, qf[ks], sacc[0], 0, 0, 0);
            sacc[1] = __builtin_amdgcn_mfma_f32_32x32x16_bf16(kf1, qf[ks], sacc[1], 0, 0, 0);
        }
        __builtin_amdgcn_s_setprio(0);

        // ---- in-lane online softmax (log2 domain) ----
        float mx = halfmax(vmax32(sacc[0], sacc[1]));
        if (!__all(mx <= mrun + RESCALE_THR)) {
            float mnew = fmaxf(mrun, mx);
            float alpha = __builtin_amdgcn_exp2f(mrun - mnew);
            #pragma unroll
            for (int dhb = 0; dhb < 4; ++dhb)
                #pragma unroll
                for (int i = 0; i < 16; ++i) oacc[dhb][i] *= alpha;
            lrun *= alpha;
            mrun = mnew;
        }
        #pragma unroll
        for (int tb = 0; tb < 2; ++tb)
            #pragma unroll
            for (int i = 0; i < 16; ++i)
                sacc[tb][i] = __builtin_amdgcn_exp2f(sacc[tb][i] - mrun);
        lrun += halfadd(vsum32(sacc[0], sacc[1]));

        // ---- P^T -> PV B-operand frags via cvt_pk + permlane32_swap ----
        bf16x8 pf[4];
        #pragma unroll
        for (int tb = 0; tb < 2; ++tb)
            #pragma unroll
            for (int ksl = 0; ksl < 2; ++ksl) {
                const int g0 = ksl * 8;
                unsigned wa0 = cvtpk(sacc[tb][g0 + 0], sacc[tb][g0 + 1]);
                unsigned wb0 = cvtpk(sacc[tb][g0 + 4], sacc[tb][g0 + 5]);
                unsigned wa1 = cvtpk(sacc[tb][g0 + 2], sacc[tb][g0 + 3]);
                unsigned wb1 = cvtpk(sacc[tb][g0 + 6], sacc[tb][g0 + 7]);
                iv2 r0 = permswap(wa0, wb0);  // -> (word0, word2)
                iv2 r1 = permswap(wa1, wb1);  // -> (word1, word3)
                union { int u[4]; bf16x8 v; } pk;
                pk.u[0] = r0[0]; pk.u[1] = r1[0]; pk.u[2] = r0[1]; pk.u[3] = r1[1];
                pf[tb * 2 + ksl] = pk.v;
            }

        // ---- PV: O^T += V^T * P^T, 4 independent chains ----
        __builtin_amdgcn_s_setprio(1);
        #pragma unroll
        for (int dhb = 0; dhb < 4; ++dhb) {
            const int rr = ((dhb & 1) << 5) + l31;  // LDS row (dh & 63)
            #pragma unroll
            for (int ks = 0; ks < 4; ++ks) {
                const int g = (dhb >> 1) * 8 + ks * 2 + hh;  // half*8 + t-chunk
                bf16x8 vf = *(const bf16x8*)(Vsh + rr * 256 + (g ^ kmask(rr)) * 16);
                oacc[dhb] = __builtin_amdgcn_mfma_f32_32x32x16_bf16(vf, pf[ks], oacc[dhb], 0, 0, 0);
            }
        }
        __builtin_amdgcn_s_setprio(0);

        // drains vmcnt(0) (prefetch landed) + syncs all waves before buffer swap
        __syncthreads();
    }

    // ---- epilogue: divide by l (lane-local), store O^T packed 4-bf16 ----
    const float inv = 1.0f / lrun;
    const int s = s0 + l31;
    #pragma unroll
    for (int dhb = 0; dhb < 4; ++dhb)
        #pragma unroll
        for (int g = 0; g < 4; ++g) {
            bf16x4 o4;
            #pragma unroll
            for (int r = 0; r < 4; ++r) o4[r] = (bf16)(oacc[dhb][g * 4 + r] * inv);
            int dh = dhb * 32 + g * 8 + hh * 4;
            *(bf16x4*)(ab + ((size_t)(b * 2048 + s)) * 2048 + h * 128 + dh) = o4;
        }
}

// ---------------- launch ----------------
extern "C" void kernel_launch(void* const* d_in, const int* in_sizes, int n_in,
                              void* d_out, int out_size, void* d_ws, size_t ws_size,
                              hipStream_t stream) {
    const float* x        = (const float*)d_in[0];
    const float* cached_k = (const float*)d_in[1];
    const float* cached_v = (const float*)d_in[2];
    const float* W_q      = (const float*)d_in[3];
    const float* W_k      = (const float*)d_in[4];
    const float* W_v      = (const float*)d_in[5];
    const float* W_o      = (const float*)d_in[6];

    float* out  = (float*)d_out;
    float* kout = out + 8388608;
    float* vout = out + 25165824;

    char* ws = (char*)d_ws;
    size_t off = 0;
    auto alloc = [&](size_t elts) { bf16* p = (bf16*)(ws + off); off += elts * 2; return p; };
    bf16* xb  = alloc(8388608);
    bf16* wqb = alloc(4194304);   // wqb/wkb/wvb contiguous => B[6144,2048] for fused QKV
    bf16* wkb = alloc(4194304);
    bf16* wvb = alloc(4194304);
    bf16* wob = alloc(4194304);
    bf16* qb  = alloc(8388608);
    bf16* kb  = alloc(16777216);
    bf16* vtb = alloc(16777216);
    bf16* ab  = alloc(8388608);
    (void)wkb; (void)wvb;

    conv_all<<<24576, 256, 0, stream>>>(x, W_q, W_k, W_v, W_o, xb, wqb);
    copy_cache_k<<<8192, 256, 0, stream>>>(cached_k, kout, kb);
    copy_cache_v<<<dim3(64, 4, 32), dim3(32, 8), 0, stream>>>(cached_v, vout, vtb);

    gemm_qkv<<<1536, 256, 0, stream>>>(xb, wqb, kout, vout, qb, kb);
    transpose_vnew<<<dim3(64, 4, 32), dim3(32, 8), 0, stream>>>(vout, vtb);

    flash_attn<<<512, 256, 0, stream>>>(qb, kb, vtb, ab);

    gemm_out<<<512, 256, 0, stream>>>(ab, wob, out);
}

// Round 5
// 628.409 us; speedup vs baseline: 1.2937x; 1.0216x over previous
//
#include <hip/hip_runtime.h>

typedef __bf16 bf16;
typedef __bf16 bf16x4 __attribute__((ext_vector_type(4)));
typedef __bf16 bf16x8 __attribute__((ext_vector_type(8)));
typedef float f32x4 __attribute__((ext_vector_type(4)));
typedef float f32x16 __attribute__((ext_vector_type(16)));
typedef int iv2 __attribute__((ext_vector_type(2)));

#define LOG2E 1.44269504088896340736f
// 1/sqrt(128) * log2(e), folded into Q at projection time -> softmax runs in log2 domain
#define QSCALE 0.12751884935f
// defer-max threshold (log2 domain): skip O-rescale while max grows <= 8 -> P <= 256
#define RESCALE_THR 8.0f

// ---------------- async global->LDS (width 16) ----------------
__device__ __forceinline__ void gload_lds16(const void* gp, void* lp) {
    __builtin_amdgcn_global_load_lds(
        (__attribute__((address_space(1))) void*)gp,
        (__attribute__((address_space(3))) void*)lp,
        16, 0, 0);
}

// Row-dependent swizzle mask for 256B rows (16 x 16B chunks), self-inverse per row.
__device__ __forceinline__ int kmask(int r) {
    return (r & 15) ^ (((r >> 5) & 1) << 2);
}

// v_cvt_pk_bf16_f32: pack two f32 -> one u32 of 2 bf16 (no builtin on gfx950)
__device__ __forceinline__ unsigned cvtpk(float lo, float hi) {
    unsigned w;
    asm("v_cvt_pk_bf16_f32 %0, %1, %2" : "=v"(w) : "v"(lo), "v"(hi));
    return w;
}

// permlane32_swap: d_new = {d[0:31], s[0:31]}, s_new = {d[32:63], s[32:63]}
__device__ __forceinline__ iv2 permswap(unsigned a, unsigned b) {
    return __builtin_amdgcn_permlane32_swap((int)a, (int)b, false, false);
}
__device__ __forceinline__ float halfmax(float v) {
    iv2 r = permswap(__float_as_uint(v), __float_as_uint(v));
    return fmaxf(__int_as_float(r[0]), __int_as_float(r[1]));
}
__device__ __forceinline__ float halfadd(float v) {
    iv2 r = permswap(__float_as_uint(v), __float_as_uint(v));
    return __int_as_float(r[0]) + __int_as_float(r[1]);
}

// tree max / sum over two f32x16 (31 ops, depth ~5)
__device__ __forceinline__ float vmax32(const f32x16& a, const f32x16& b) {
    float t[8];
    #pragma unroll
    for (int i = 0; i < 8; ++i)
        t[i] = fmaxf(fmaxf(a[i], a[i + 8]), fmaxf(b[i], b[i + 8]));
    return fmaxf(fmaxf(fmaxf(t[0], t[1]), fmaxf(t[2], t[3])),
                 fmaxf(fmaxf(t[4], t[5]), fmaxf(t[6], t[7])));
}
__device__ __forceinline__ float vsum32(const f32x16& a, const f32x16& b) {
    float t[8];
    #pragma unroll
    for (int i = 0; i < 8; ++i)
        t[i] = (a[i] + a[i + 8]) + (b[i] + b[i + 8]);
    return ((t[0] + t[1]) + (t[2] + t[3])) + ((t[4] + t[5]) + (t[6] + t[7]));
}

// ---------------- fp32 -> bf16 convert: x + 4 weights in ONE launch ----------------
__global__ void conv_all(const float* __restrict__ x, const float* __restrict__ wq,
                         const float* __restrict__ wk, const float* __restrict__ wv,
                         const float* __restrict__ wo, bf16* __restrict__ xb,
                         bf16* __restrict__ wbase) {
    int id = blockIdx.x;
    const float* src;
    bf16* dst;
    int i;
    if (id < 8192) {
        src = x; dst = xb;
        i = id * 256 + threadIdx.x;
    } else {
        int w = (id - 8192) >> 12;
        src = (w == 0) ? wq : (w == 1) ? wk : (w == 2) ? wv : wo;
        dst = wbase + (size_t)w * 4194304;
        i = ((id - 8192) & 4095) * 256 + threadIdx.x;
    }
    float4 f = ((const float4*)src)[i];
    bf16x4 v;
    v[0] = (bf16)f.x; v[1] = (bf16)f.y; v[2] = (bf16)f.z; v[3] = (bf16)f.w;
    *(bf16x4*)(dst + (size_t)i * 4) = v;
}

// ---------------- cached_k -> d_out(k, t<2048) fp32 + kb bf16 ----------------
__global__ void copy_cache_k(const float* __restrict__ ck, float* __restrict__ kout,
                             bf16* __restrict__ kb) {
    size_t i = ((size_t)blockIdx.x * 256 + threadIdx.x) * 4;
    size_t bh  = i >> 18;
    size_t rem = i & 262143;
    size_t o   = (bh << 19) + rem;
    float4 f = *(const float4*)(ck + i);
    *(float4*)(kout + o) = f;
    bf16x4 v;
    v[0] = (bf16)f.x; v[1] = (bf16)f.y; v[2] = (bf16)f.z; v[3] = (bf16)f.w;
    *(bf16x4*)(kb + o) = v;
}

// ---------------- cached_v -> d_out(v, t<2048) fp32 + vtb bf16 transposed ----------------
__global__ void copy_cache_v(const float* __restrict__ cv, float* __restrict__ vout,
                             bf16* __restrict__ vtb) {
    __shared__ float tile[32][33];
    int bh = blockIdx.z;
    int t0 = blockIdx.x * 32;
    int dh0 = blockIdx.y * 32;
    int tx = threadIdx.x, ty = threadIdx.y;
    const float* src = cv + (size_t)bh * 2048 * 128;
    float* dstf = vout + (size_t)bh * 4096 * 128;
    #pragma unroll
    for (int i = 0; i < 4; ++i) {
        int t = t0 + ty * 4 + i;
        float val = src[(size_t)t * 128 + dh0 + tx];
        dstf[(size_t)t * 128 + dh0 + tx] = val;
        tile[ty * 4 + i][tx] = val;
    }
    __syncthreads();
    bf16* dstb = vtb + (size_t)bh * 128 * 4096;
    #pragma unroll
    for (int i = 0; i < 4; ++i) {
        int dh = dh0 + ty * 4 + i;
        dstb[(size_t)dh * 4096 + t0 + tx] = (bf16)tile[tx][ty * 4 + i];
    }
}

// ---------------- vout(t in [2048,4096)) fp32 -> vtb bf16 transposed ----------------
__global__ void transpose_vnew(const float* __restrict__ vout, bf16* __restrict__ vtb) {
    __shared__ float tile[32][33];
    int bh = blockIdx.z;
    int t0 = 2048 + blockIdx.x * 32;
    int dh0 = blockIdx.y * 32;
    int tx = threadIdx.x, ty = threadIdx.y;
    const float* src = vout + (size_t)bh * 4096 * 128;
    #pragma unroll
    for (int i = 0; i < 4; ++i) {
        int t = t0 + ty * 4 + i;
        tile[ty * 4 + i][tx] = src[(size_t)t * 128 + dh0 + tx];
    }
    __syncthreads();
    bf16* dstb = vtb + (size_t)bh * 128 * 4096;
    #pragma unroll
    for (int i = 0; i < 4; ++i) {
        int dh = dh0 + ty * 4 + i;
        dstb[(size_t)dh * 4096 + t0 + tx] = (bf16)tile[tx][ty * 4 + i];
    }
}

// ---------------- fused QKV NT GEMM v2: 256x256 tile, counted-vmcnt ring pipeline -----
// C[4096,6144] = xb[4096,2048] * Wqkv[6144,2048]^T.
// 512 thr (8 waves 2Mx4N, 128x64 out per wave), BK=32, LDS = 4 ring slots x 32 KB.
// Per iter: issue stage(kt+2) -> s_waitcnt vmcnt(8) (tiles kt+1,kt+2 stay in flight;
// guarantees kt landed for THIS wave) -> s_barrier (all waves' kt landed) -> ds_read+MFMA.
// NO vmcnt(0) drain in the main loop (T4). Slot hazard: reads kt&3; writes target
// (kt+1)&3,(kt+2)&3; max skew <1 iter puts a leader's stage(kt+3) in (kt-1)&3 - all
// distinct mod 4. LDS swizzle: chunk ^= (row>>1)&3 on 64B rows (pre-swizzled global
// source, linear LDS dest - same proven pattern as flash, 0 conflicts).
__global__ __launch_bounds__(512, 2)
void gemm_qkv(const bf16* __restrict__ A, const bf16* __restrict__ Bm,
              float* __restrict__ kout, float* __restrict__ vout,
              bf16* __restrict__ qb, bf16* __restrict__ kb) {
    const int K = 2048, NKT = 64;  // 64 K-tiles of 32
    __shared__ __align__(16) char smem[131072];  // 4 slots x (A 16K + B 16K)
    const int tid = threadIdx.x;
    const int wid = tid >> 6;
    const int lane = tid & 63;
    const int quad = lane >> 4;
    const int l16 = lane & 15;
    // N-partition XCD map (384 blocks = 16 m-panels x 24 n-panels): xcd owns 3 n-panels
    // (3 MB of B resident in its L2); m-outer sweep; A dedups via L3.
    const int wg = blockIdx.x;
    const int xcd = wg & 7;
    const int i_x = wg >> 3;                    // 0..47
    const int m0 = (i_x / 3) * 256;             // 16 panels
    const int n0 = (xcd * 3 + i_x % 3) * 256;   // 24 panels
    const int wm = (wid >> 2) * 128;            // wave M offset (2)
    const int wn = (wid & 3) * 64;              // wave N offset (4)

    f32x4 zero = {0.f, 0.f, 0.f, 0.f};
    f32x4 acc[8][4];
    #pragma unroll
    for (int i = 0; i < 8; ++i)
        #pragma unroll
        for (int j = 0; j < 4; ++j) acc[i][j] = zero;

    const int ldsw = (tid & ~63) * 16;  // wave-uniform part of the linear LDS dest

    auto stage = [&](int kt) {
        char* slot = smem + (kt & 3) * 32768;
        const bf16* ga = A + (size_t)m0 * K + kt * 32;
        const bf16* gb = Bm + (size_t)n0 * K + kt * 32;
        #pragma unroll
        for (int i = 0; i < 2; ++i) {
            int c = i * 512 + tid;
            int row = c >> 2, j = c & 3;
            int jg = j ^ ((row >> 1) & 3);
            gload_lds16(ga + (size_t)row * K + jg * 8, slot + ldsw + i * 8192);
        }
        #pragma unroll
        for (int i = 0; i < 2; ++i) {
            int c = i * 512 + tid;
            int row = c >> 2, j = c & 3;
            int jg = j ^ ((row >> 1) & 3);
            gload_lds16(gb + (size_t)row * K + jg * 8, slot + 16384 + ldsw + i * 8192);
        }
    };

    stage(0);
    stage(1);

    #pragma unroll 1
    for (int kt = 0; kt < NKT; ++kt) {
        if (kt + 2 < NKT) {
            stage(kt + 2);
            asm volatile("s_waitcnt vmcnt(8)" ::: "memory");
        } else if (kt + 1 < NKT) {
            asm volatile("s_waitcnt vmcnt(4)" ::: "memory");
        } else {
            asm volatile("s_waitcnt vmcnt(0)" ::: "memory");
        }
        __builtin_amdgcn_s_barrier();
        asm volatile("" ::: "memory");  // keep ds_reads below the barrier

        const char* slot = smem + (kt & 3) * 32768;
        bf16x8 af[8], bfv[4];
        #pragma unroll
        for (int mi = 0; mi < 8; ++mi) {
            int row = wm + mi * 16 + l16;
            af[mi] = *(const bf16x8*)(slot + row * 64 + (quad ^ ((row >> 1) & 3)) * 16);
        }
        #pragma unroll
        for (int ni = 0; ni < 4; ++ni) {
            int row = wn + ni * 16 + l16;
            bfv[ni] = *(const bf16x8*)(slot + 16384 + row * 64 + (quad ^ ((row >> 1) & 3)) * 16);
        }
        __builtin_amdgcn_s_setprio(1);
        #pragma unroll
        for (int mi = 0; mi < 8; ++mi)
            #pragma unroll
            for (int ni = 0; ni < 4; ++ni)
                acc[mi][ni] = __builtin_amdgcn_mfma_f32_16x16x32_bf16(af[mi], bfv[ni], acc[mi][ni], 0, 0, 0);
        __builtin_amdgcn_s_setprio(0);
    }

    const int seg = n0 >> 11;  // 0=Q, 1=K, 2=V (uniform per block; 256-tile within seg)
    #pragma unroll
    for (int mi = 0; mi < 8; ++mi)
        #pragma unroll
        for (int ni = 0; ni < 4; ++ni)
            #pragma unroll
            for (int r = 0; r < 4; ++r) {
                int grow = m0 + wm + mi * 16 + quad * 4 + r;
                int gcol = n0 + wn + ni * 16 + l16;
                float v = acc[mi][ni][r];
                int b = grow >> 11, s = grow & 2047;
                int c2 = gcol & 2047;
                int h = c2 >> 7, dh = c2 & 127;
                if (seg == 0) {
                    qb[(((size_t)(b * 16 + h) * 2048) + s) * 128 + dh] = (bf16)(v * QSCALE);
                } else if (seg == 1) {
                    size_t idx = (((size_t)(b * 16 + h) * 4096) + 2048 + s) * 128 + dh;
                    kout[idx] = v;
                    kb[idx] = (bf16)v;
                } else {
                    size_t idx = (((size_t)(b * 16 + h) * 4096) + 2048 + s) * 128 + dh;
                    vout[idx] = v;
                }
            }
}

// ---------------- output NT GEMM: out[4096,2048] = ab * Wo^T ----------------
// XCD N-partition: each XCD owns 2 n-panels (1 MB of B, L2-resident for the kernel).
__global__ __launch_bounds__(256)
void gemm_out(const bf16* __restrict__ A, const bf16* __restrict__ Bm,
              float* __restrict__ out_f32) {
    const int K = 2048, N = 2048;
    __shared__ __align__(16) char smem[32768];
    const int tid = threadIdx.x;
    const int wid = tid >> 6;
    const int lane = tid & 63;
    const int quad = lane >> 4;
    const int l16 = lane & 15;
    const int wg = blockIdx.x;
    const int xcd = wg & 7;
    const int i_x = wg >> 3;                  // 0..63
    const int m0 = (i_x >> 1) * 128;          // 0..31 panels
    const int n0 = (xcd * 2 + (i_x & 1)) * 128;  // 0..15 panels
    const int wm = (wid & 1) * 64;
    const int wn = (wid >> 1) * 64;

    f32x4 zero = {0.f, 0.f, 0.f, 0.f};
    f32x4 acc[4][4];
    #pragma unroll
    for (int i = 0; i < 4; ++i)
        #pragma unroll
        for (int j = 0; j < 4; ++j) acc[i][j] = zero;

    auto stage = [&](int k0, int buf) {
        char* base = smem + buf * 16384;
        #pragma unroll
        for (int t = 0; t < 2; ++t) {
            int c = t * 256 + tid;
            int row = c >> 2, kc = c & 3;
            const char* gA = (const char*)(A + (size_t)(m0 + row) * K + k0 + kc * 8);
            const char* gB = (const char*)(Bm + (size_t)(n0 + row) * K + k0 + kc * 8);
            char* lA = base + (size_t)(t * 256 + (tid & ~63)) * 16;
            char* lB = base + 8192 + (size_t)(t * 256 + (tid & ~63)) * 16;
            gload_lds16(gA, lA);
            gload_lds16(gB, lB);
        }
    };

    stage(0, 0);
    __syncthreads();

    for (int k0 = 0; k0 < K; k0 += 32) {
        const int cur = (k0 >> 5) & 1;
        if (k0 + 32 < K) stage(k0 + 32, cur ^ 1);
        const char* base = smem + cur * 16384;
        bf16x8 af[4], bfv[4];
        #pragma unroll
        for (int i = 0; i < 4; ++i) {
            af[i]  = *(const bf16x8*)(base + ((wm + i * 16 + l16) * 32 + quad * 8) * 2);
            bfv[i] = *(const bf16x8*)(base + 8192 + ((wn + i * 16 + l16) * 32 + quad * 8) * 2);
        }
        __builtin_amdgcn_s_setprio(1);
        #pragma unroll
        for (int i = 0; i < 4; ++i)
            #pragma unroll
            for (int j = 0; j < 4; ++j)
                acc[i][j] = __builtin_amdgcn_mfma_f32_16x16x32_bf16(af[i], bfv[j], acc[i][j], 0, 0, 0);
        __builtin_amdgcn_s_setprio(0);
        __syncthreads();
    }

    #pragma unroll
    for (int i = 0; i < 4; ++i)
        #pragma unroll
        for (int j = 0; j < 4; ++j)
            #pragma unroll
            for (int r = 0; r < 4; ++r) {
                int grow = m0 + wm + i * 16 + quad * 4 + r;
                int gcol = n0 + wn + j * 16 + l16;
                out_f32[(size_t)grow * N + gcol] = acc[i][j][r];
            }
}

// ---------------- flash attention v6: swapped 32x32, 4-bit LDS swizzle ----------------
// qb (B,H,2048,128) bf16 PRE-SCALED; kb (B,H,4096,128); vtb (B,H,128,4096) -> ab (B,S,2048)
__global__ __launch_bounds__(256, 2)
void flash_attn(const bf16* __restrict__ qb, const bf16* __restrict__ kb,
                const bf16* __restrict__ vtb, bf16* __restrict__ ab) {
    __shared__ __align__(16) char smem[65536];
    const int tid = threadIdx.x;
    const int wid = tid >> 6;
    const int lane = tid & 63;
    const int hh = lane >> 5;   // lane half
    const int l31 = lane & 31;  // q within wave tile / row within 32-block

    // XCD swizzle: flat = 512 blocks; same head -> same XCD
    const int flat = blockIdx.x;
    const int xcd = flat & 7;
    const int idx = flat >> 3;
    const int bh = xcd * 4 + (idx >> 4);
    const int qblk = idx & 15;
    const int b = bh >> 4, h = bh & 15;
    const int s0 = qblk * 128 + wid * 32;

    const bf16* Q  = qb  + (size_t)bh * 2048 * 128;
    const bf16* Kp = kb  + (size_t)bh * 4096 * 128;
    const bf16* Vt = vtb + (size_t)bh * 128 * 4096;

    // Q fragments (B-operand of mfma(K,Q)): col=q=lane&31, k=dh=ks*16+hh*8+j
    bf16x8 qf[8];
    #pragma unroll
    for (int ks = 0; ks < 8; ++ks)
        qf[ks] = *(const bf16x8*)(Q + (size_t)(s0 + l31) * 128 + ks * 16 + hh * 8);

    f32x16 oacc[4];  // O^T: rows dh (dhb*32 + (reg&3)+8*(reg>>2)+4*hh), col q=lane&31
    #pragma unroll
    for (int dhb = 0; dhb < 4; ++dhb)
        #pragma unroll
        for (int i = 0; i < 16; ++i) oacc[dhb][i] = 0.f;
    float mrun = -1e30f, lrun = 0.f;

    auto stage = [&](int t0, int buf) {
        char* Kb = smem + buf * 32768;
        char* Vb = Kb + 16384;
        // K: 64 rows x 256B; slot j at row holds global chunk j ^ kmask(row)
        #pragma unroll
        for (int r4 = 0; r4 < 4; ++r4) {
            int kc = r4 * 256 + tid;
            int row = kc >> 4, p = kc & 15;
            int j = p ^ kmask(row);
            gload_lds16(Kp + (size_t)(t0 + row) * 128 + j * 8, Kb + kc * 16);
        }
        // V: 64 rows x 256B; row r slot j holds chunk g = j ^ kmask(r),
        //    g = half*8 + p -> dh = r + half*64, t-chunk p
        #pragma unroll
        for (int r4 = 0; r4 < 4; ++r4) {
            int vc = r4 * 256 + tid;
            int row = vc >> 4, j = vc & 15;
            int g = j ^ kmask(row);
            int dh = row + (g >> 3) * 64;
            int p = g & 7;
            gload_lds16(Vt + (size_t)dh * 4096 + t0 + p * 8, Vb + vc * 16);
        }
    };

    stage(0, 0);
    __syncthreads();  // implicit vmcnt(0): buf0 resident

    for (int t0 = 0; t0 < 4096; t0 += 64) {
        const int cur = (t0 >> 6) & 1;
        if (t0 + 64 < 4096) stage(t0 + 64, cur ^ 1);  // prefetch under this tile's compute
        const char* Ksh = smem + cur * 32768;
        const char* Vsh = Ksh + 16384;

        // ---- QK^T: S^T[t][q], two 32-t blocks, two independent MFMA chains ----
        f32x16 sacc[2];
        #pragma unroll
        for (int i = 0; i < 16; ++i) { sacc[0][i] = 0.f; sacc[1][i] = 0.f; }
        __builtin_amdgcn_s_setprio(1);
        #pragma unroll
        for (int ks = 0; ks < 8; ++ks) {
            const int c = ks * 2 + hh;
            const int r0 = l31, r1 = 32 + l31;
            bf16x8 kf0 = *(const bf16x8*)(Ksh + r0 * 256 + (c ^ kmask(r0)) * 16);
            bf16x8 kf1 = *(const bf16x8*)(Ksh + r1 * 256 + (c ^ kmask(r1)) * 16);
            sacc[0] = __builtin_amdgcn_mfma_f32_32x32x16_bf16(kf0, qf[ks], sacc[0], 0, 0, 0);
            sacc[1] = __builtin_amdgcn_mfma_f32_32x32x16_bf16(kf1, qf[ks], sacc[1], 0, 0, 0);
        }
        __builtin_amdgcn_s_setprio(0);

        // ---- in-lane online softmax (log2 domain) ----
        float mx = halfmax(vmax32(sacc[0], sacc[1]));
        if (!__all(mx <= mrun + RESCALE_THR)) {
            float mnew = fmaxf(mrun, mx);
            float alpha = __builtin_amdgcn_exp2f(mrun - mnew);
            #pragma unroll
            for (int dhb = 0; dhb < 4; ++dhb)
                #pragma unroll
                for (int i = 0; i < 16; ++i) oacc[dhb][i] *= alpha;
            lrun *= alpha;
            mrun = mnew;
        }
        #pragma unroll
        for (int tb = 0; tb < 2; ++tb)
            #pragma unroll
            for (int i = 0; i < 16; ++i)
                sacc[tb][i] = __builtin_amdgcn_exp2f(sacc[tb][i] - mrun);
        lrun += halfadd(vsum32(sacc[0], sacc[1]));

        // ---- P^T -> PV B-operand frags via cvt_pk + permlane32_swap ----
        bf16x8 pf[4];
        #pragma unroll
        for (int tb = 0; tb < 2; ++tb)
            #pragma unroll
            for (int ksl = 0; ksl < 2; ++ksl) {
                const int g0 = ksl * 8;
                unsigned wa0 = cvtpk(sacc[tb][g0 + 0], sacc[tb][g0 + 1]);
                unsigned wb0 = cvtpk(sacc[tb][g0 + 4], sacc[tb][g0 + 5]);
                unsigned wa1 = cvtpk(sacc[tb][g0 + 2], sacc[tb][g0 + 3]);
                unsigned wb1 = cvtpk(sacc[tb][g0 + 6], sacc[tb][g0 + 7]);
                iv2 r0 = permswap(wa0, wb0);  // -> (word0, word2)
                iv2 r1 = permswap(wa1, wb1);  // -> (word1, word3)
                union { int u[4]; bf16x8 v; } pk;
                pk.u[0] = r0[0]; pk.u[1] = r1[0]; pk.u[2] = r0[1]; pk.u[3] = r1[1];
                pf[tb * 2 + ksl] = pk.v;
            }

        // ---- PV: O^T += V^T * P^T, 4 independent chains ----
        __builtin_amdgcn_s_setprio(1);
        #pragma unroll
        for (int dhb = 0; dhb < 4; ++dhb) {
            const int rr = ((dhb & 1) << 5) + l31;  // LDS row (dh & 63)
            #pragma unroll
            for (int ks = 0; ks < 4; ++ks) {
                const int g = (dhb >> 1) * 8 + ks * 2 + hh;  // half*8 + t-chunk
                bf16x8 vf = *(const bf16x8*)(Vsh + rr * 256 + (g ^ kmask(rr)) * 16);
                oacc[dhb] = __builtin_amdgcn_mfma_f32_32x32x16_bf16(vf, pf[ks], oacc[dhb], 0, 0, 0);
            }
        }
        __builtin_amdgcn_s_setprio(0);

        // drains vmcnt(0) (prefetch landed) + syncs all waves before buffer swap
        __syncthreads();
    }

    // ---- epilogue: divide by l (lane-local), store O^T packed 4-bf16 ----
    const float inv = 1.0f / lrun;
    const int s = s0 + l31;
    #pragma unroll
    for (int dhb = 0; dhb < 4; ++dhb)
        #pragma unroll
        for (int g = 0; g < 4; ++g) {
            bf16x4 o4;
            #pragma unroll
            for (int r = 0; r < 4; ++r) o4[r] = (bf16)(oacc[dhb][g * 4 + r] * inv);
            int dh = dhb * 32 + g * 8 + hh * 4;
            *(bf16x4*)(ab + ((size_t)(b * 2048 + s)) * 2048 + h * 128 + dh) = o4;
        }
}

// ---------------- launch ----------------
extern "C" void kernel_launch(void* const* d_in, const int* in_sizes, int n_in,
                              void* d_out, int out_size, void* d_ws, size_t ws_size,
                              hipStream_t stream) {
    const float* x        = (const float*)d_in[0];
    const float* cached_k = (const float*)d_in[1];
    const float* cached_v = (const float*)d_in[2];
    const float* W_q      = (const float*)d_in[3];
    const float* W_k      = (const float*)d_in[4];
    const float* W_v      = (const float*)d_in[5];
    const float* W_o      = (const float*)d_in[6];

    float* out  = (float*)d_out;
    float* kout = out + 8388608;
    float* vout = out + 25165824;

    char* ws = (char*)d_ws;
    size_t off = 0;
    auto alloc = [&](size_t elts) { bf16* p = (bf16*)(ws + off); off += elts * 2; return p; };
    bf16* xb  = alloc(8388608);
    bf16* wqb = alloc(4194304);   // wqb/wkb/wvb contiguous => B[6144,2048] for fused QKV
    bf16* wkb = alloc(4194304);
    bf16* wvb = alloc(4194304);
    bf16* wob = alloc(4194304);
    bf16* qb  = alloc(8388608);
    bf16* kb  = alloc(16777216);
    bf16* vtb = alloc(16777216);
    bf16* ab  = alloc(8388608);
    (void)wkb; (void)wvb;

    conv_all<<<24576, 256, 0, stream>>>(x, W_q, W_k, W_v, W_o, xb, wqb);
    copy_cache_k<<<8192, 256, 0, stream>>>(cached_k, kout, kb);
    copy_cache_v<<<dim3(64, 4, 32), dim3(32, 8), 0, stream>>>(cached_v, vout, vtb);

    gemm_qkv<<<384, 512, 0, stream>>>(xb, wqb, kout, vout, qb, kb);
    transpose_vnew<<<dim3(64, 4, 32), dim3(32, 8), 0, stream>>>(vout, vtb);

    flash_attn<<<512, 256, 0, stream>>>(qb, kb, vtb, ab);

    gemm_out<<<512, 256, 0, stream>>>(ab, wob, out);
}